// Round 19
// baseline (588.982 us; speedup 1.0000x reference)
//
#include <hip/hip_runtime.h>
#include <hip/hip_bf16.h>
#include <hip/hip_fp16.h>

#define TT 24
#define FF 16
#define HH 64
#define GG 192   // 3*HH
#define ELLW 96  // ELL stride; Poisson(32) max deg ~66 << 96
#define AROW 396 // agg_lds row stride (198 dwords == 6 mod 32 -> conflict-free b128)

typedef __attribute__((ext_vector_type(4))) float f32x4;
typedef __attribute__((ext_vector_type(8))) _Float16 f16x8;

__device__ __forceinline__ float fast_rcp(float x){ return __builtin_amdgcn_rcpf(x); }
__device__ __forceinline__ float sigmoid_f(float x){
  return fast_rcp(1.0f + __expf(-x));
}
__device__ __forceinline__ float tanh_f(float x){
  float e = __expf(-2.0f * fabsf(x));
  float th = (1.0f - e) * fast_rcp(1.0f + e);
  return copysignf(th, x);
}
__device__ __forceinline__ uint pack_h2(float a, float b){
  ushort ha = __half_as_ushort(__float2half(a));
  ushort hb = __half_as_ushort(__float2half(b));
  return (uint)ha | ((uint)hb << 16);
}
__device__ __forceinline__ void acc8(float* a, uint4 u, float w){
  __half2 p0 = *(__half2*)&u.x, p1 = *(__half2*)&u.y;
  __half2 p2 = *(__half2*)&u.z, p3 = *(__half2*)&u.w;
  float2 f0 = __half22float2(p0), f1 = __half22float2(p1);
  float2 f2 = __half22float2(p2), f3 = __half22float2(p3);
  a[0] += w*f0.x; a[1] += w*f0.y; a[2] += w*f1.x; a[3] += w*f1.y;
  a[4] += w*f2.x; a[5] += w*f2.y; a[6] += w*f3.x; a[7] += w*f3.y;
}
__device__ __forceinline__ void acc4(float* a, uint2 u, float w){
  __half2 p0 = *(__half2*)&u.x, p1 = *(__half2*)&u.y;
  float2 f0 = __half22float2(p0), f1 = __half22float2(p1);
  a[0] += w*f0.x; a[1] += w*f0.y; a[2] += w*f1.x; a[3] += w*f1.y;
}

// ---------------- fused prologue: xt2 || ELL-fill (ushort) || prep ----------------
__global__ __launch_bounds__(256)
void k_pre2(const float* __restrict__ x, ushort* __restrict__ xTh,
            const int* __restrict__ ei, int E, int* __restrict__ cnt, ushort* __restrict__ ell,
            const float* __restrict__ gcn_w, const float* __restrict__ gcn_b,
            const float* __restrict__ w_ih, const float* __restrict__ b_ih,
            const float* __restrict__ w_hh,
            ushort* __restrict__ m1F, float* __restrict__ c1, ushort* __restrict__ whhF,
            int N, int GX, int GD){
  __shared__ ushort tile[16][392];
  const int bid = blockIdx.x;
  const int tid = threadIdx.x;
  if(bid < GX){
    const int nbase = bid * 16;
    const int nd = tid >> 4, f = tid & 15;
    const int n = nbase + nd;
    for(int t=0; t<TT; t++){
      float v = (n < N) ? x[((size_t)t*N + n)*FF + f] : 0.f;
      tile[nd][t*16 + f] = __half_as_ushort(__float2half(v));
    }
    __syncthreads();
    uint* xo = (uint*)xTh;
    for(int i = tid; i < 16*192; i += 256){
      int d = i / 192, pos = i - d*192;
      int nn = nbase + d;
      if(nn < N) xo[(size_t)nn*192 + pos] = *(uint*)&tile[d][pos*2];
    }
  } else if(bid < GX + GD){
    // single-pass ELL build: cnt doubles as degree
    int i = (bid - GX)*256 + tid;
    if(i < E){
      int s = ei[i], d = ei[E+i];
      int slot = atomicAdd(&cnt[d], 1);
      if(slot < ELLW) ell[(size_t)d*ELLW + slot] = (ushort)s;
    }
  } else {
    int t2 = (bid - GX - GD)*256 + tid;
    if(t2 < GG*FF){
      int j = t2 >> 4, f = t2 & 15;
      float s = 0.f;
      for(int k=0;k<HH;k++) s += gcn_w[f*HH+k]*w_ih[j*HH+k];
      m1F[t2] = __half_as_ushort(__float2half(s));
    } else if (t2 < GG*FF + GG){
      int j = t2 - GG*FF;
      float s = b_ih[j];
      for(int k=0;k<HH;k++) s += gcn_b[k]*w_ih[j*HH+k];
      c1[j] = s;
    }
    if(t2 < GG*HH){
      whhF[t2] = __half_as_ushort(__float2half(w_hh[t2]));
    }
  }
}

// ---------------- fused agg + GRU + head: block = 16 nodes, 4 waves ----------------
__global__ __launch_bounds__(256, 8)
void k_fused(const ushort* __restrict__ xTh, const int* __restrict__ cnt,
             const ushort* __restrict__ ell,
             const ushort* __restrict__ whhF, const ushort* __restrict__ m1F,
             const float* __restrict__ c1, const float* __restrict__ bhh,
             const float* __restrict__ lin_w, const float* __restrict__ lin_b,
             float* __restrict__ out, int N, int P){
  __shared__ __align__(16) ushort agg_lds[16][AROW];  // pos = t*16+f, stride conflict-free
  __shared__ __align__(16) uint hb[2][512];           // 4 KB h dbuf (f16)
  const int tid = threadIdx.x;
  const int l = tid & 63, w = tid >> 6;
  const int half = l >> 5, lh = l & 31;
  const int nbase = blockIdx.x * 16;

  // zero h buffer 0 (covered by the phase-A barrier)
  for(int i=tid; i<512; i+=256) hb[0][i]=0u;

  // ---- Phase A: aggregation, 4 nodes per wave ----
  for(int q=0; q<4; q++){
    const int nl = w*4 + q;
    const int n = min(nbase + nl, N-1);
    float aA[8] = {0.f,0.f,0.f,0.f,0.f,0.f,0.f,0.f};
    float aB[4] = {0.f,0.f,0.f,0.f};
    const int cn = cnt[n];
    const float dn = rsqrtf((float)cn + 1.0f);
    const int hi = min(cn, ELLW);
    const ushort* eb = ell + (size_t)n*ELLW;

    for(int j = 0; j < hi; j += 8){
      int j0 = j     + half;
      int j1 = j + 2 + half;
      int j2 = j + 4 + half;
      int j3 = j + 6 + half;
      bool k0 = j0 < hi, k1 = j1 < hi, k2 = j2 < hi, k3 = j3 < hi;
      int s0 = n, s1 = n, s2 = n, s3 = n;
      if(k0) s0 = eb[j0];
      if(k1) s1 = eb[j1];
      if(k2) s2 = eb[j2];
      if(k3) s3 = eb[j3];
      float w0 = k0 ? rsqrtf((float)cnt[s0] + 1.0f)*dn : 0.f;
      float w1 = k1 ? rsqrtf((float)cnt[s1] + 1.0f)*dn : 0.f;
      float w2 = k2 ? rsqrtf((float)cnt[s2] + 1.0f)*dn : 0.f;
      float w3 = k3 ? rsqrtf((float)cnt[s3] + 1.0f)*dn : 0.f;
      const ushort* r0 = xTh + (size_t)s0*384;
      const ushort* r1 = xTh + (size_t)s1*384;
      const ushort* r2 = xTh + (size_t)s2*384;
      const ushort* r3 = xTh + (size_t)s3*384;
      uint4 A0 = *(const uint4*)(r0 + lh*8);
      uint4 A1 = *(const uint4*)(r1 + lh*8);
      uint4 A2 = *(const uint4*)(r2 + lh*8);
      uint4 A3 = *(const uint4*)(r3 + lh*8);
      uint2 B0 = *(const uint2*)(r0 + 256 + lh*4);
      uint2 B1 = *(const uint2*)(r1 + 256 + lh*4);
      uint2 B2 = *(const uint2*)(r2 + 256 + lh*4);
      uint2 B3 = *(const uint2*)(r3 + 256 + lh*4);
      acc8(aA, A0, w0); acc4(aB, B0, w0);
      acc8(aA, A1, w1); acc4(aB, B1, w1);
      acc8(aA, A2, w2); acc4(aB, B2, w2);
      acc8(aA, A3, w3); acc4(aB, B3, w3);
    }
    #pragma unroll
    for(int k=0;k<8;k++) aA[k] += __shfl_xor(aA[k], 32, 64);
    #pragma unroll
    for(int k=0;k<4;k++) aB[k] += __shfl_xor(aB[k], 32, 64);

    if(half == 0){
      float sn = dn*dn;
      const ushort* rS = xTh + (size_t)n*384;
      uint4 AS = *(const uint4*)(rS + lh*8);
      uint2 BS = *(const uint2*)(rS + 256 + lh*4);
      acc8(aA, AS, sn); acc4(aB, BS, sn);
      ushort* row = &agg_lds[nl][0];
      uint4 h0;
      h0.x = pack_h2(aA[0], aA[1]);
      h0.y = pack_h2(aA[2], aA[3]);
      h0.z = pack_h2(aA[4], aA[5]);
      h0.w = pack_h2(aA[6], aA[7]);
      *(uint4*)(row + lh*8) = h0;
      uint2 hB;
      hB.x = pack_h2(aB[0], aB[1]);
      hB.y = pack_h2(aB[2], aB[3]);
      *(uint2*)(row + 256 + lh*4) = hB;
    }
  }
  __syncthreads();

  // ---- Phase B: GRU ----
  const int nd = l & 15, g = l >> 4;
  const int chB = 16*w;
  const f16x8 zf = (f16x8){0,0,0,0,0,0,0,0};
  f16x8 ar0,ar1,az0,az1,an0,an1, mr,mz,mn;
  {
    const int rr =        chB + nd;
    const int rz =  HH  + chB + nd;
    const int rn = 2*HH + chB + nd;
    ar0 = *(const f16x8*)(whhF + rr*HH      + g*8);
    ar1 = *(const f16x8*)(whhF + rr*HH + 32 + g*8);
    az0 = *(const f16x8*)(whhF + rz*HH      + g*8);
    az1 = *(const f16x8*)(whhF + rz*HH + 32 + g*8);
    an0 = *(const f16x8*)(whhF + rn*HH      + g*8);
    an1 = *(const f16x8*)(whhF + rn*HH + 32 + g*8);
    mr = zf; mz = zf; mn = zf;
    if(g < 2){
      mr = *(const f16x8*)(m1F + rr*FF + g*8);
      mz = *(const f16x8*)(m1F + rz*FF + g*8);
      mn = *(const f16x8*)(m1F + rn*FF + g*8);
    } else if(g == 2){
      mr[0] = (_Float16)(c1[rr] + bhh[rr]);
      mz[0] = (_Float16)(c1[rz] + bhh[rz]);
      mn[0] = (_Float16)(c1[rn]);
    }
  }
  float4 bb = *(const float4*)(bhh + 2*HH + chB + g*4);

  float hreg[4] = {0.f,0.f,0.f,0.f};
  f16x8 cB = zf;            // bias/zero frag for g>=2
  if(g==2) cB[0] = (_Float16)1.0f;

  const int swz = (nd & 7) << 2;

  for(int t=0; t<TT; t++){
    const uint* cb = hb[t & 1];
    uint* nb = hb[(t & 1) ^ 1];

    f16x8 hB0 = *(const f16x8*)(cb + nd*32 + ((g*4)      ^ swz));
    f16x8 hB1 = *(const f16x8*)(cb + nd*32 + ((16 + g*4) ^ swz));
    f16x8 cAg = cB;
    if(g < 2) cAg = *(const f16x8*)&agg_lds[nd][t*16 + g*8];

    f32x4 R  = {0.f,0.f,0.f,0.f};
    f32x4 Z  = {0.f,0.f,0.f,0.f};
    f32x4 Nh = {0.f,0.f,0.f,0.f};
    f32x4 Ni = {0.f,0.f,0.f,0.f};
    R  = __builtin_amdgcn_mfma_f32_16x16x32_f16(ar0, hB0, R , 0,0,0);
    R  = __builtin_amdgcn_mfma_f32_16x16x32_f16(ar1, hB1, R , 0,0,0);
    R  = __builtin_amdgcn_mfma_f32_16x16x32_f16(mr,  cAg, R , 0,0,0);
    Z  = __builtin_amdgcn_mfma_f32_16x16x32_f16(az0, hB0, Z , 0,0,0);
    Z  = __builtin_amdgcn_mfma_f32_16x16x32_f16(az1, hB1, Z , 0,0,0);
    Z  = __builtin_amdgcn_mfma_f32_16x16x32_f16(mz,  cAg, Z , 0,0,0);
    Nh = __builtin_amdgcn_mfma_f32_16x16x32_f16(an0, hB0, Nh, 0,0,0);
    Nh = __builtin_amdgcn_mfma_f32_16x16x32_f16(an1, hB1, Nh, 0,0,0);
    Ni = __builtin_amdgcn_mfma_f32_16x16x32_f16(mn,  cAg, Ni, 0,0,0);

    const float bbv[4] = {bb.x, bb.y, bb.z, bb.w};
    #pragma unroll
    for(int i=0;i<4;i++){
      float r_ = sigmoid_f(R[i]);
      float z_ = sigmoid_f(Z[i]);
      float nn = tanh_f(Ni[i] + r_*(Nh[i] + bbv[i]));
      hreg[i] = nn + z_*(hreg[i] - nn);
    }
    uint2 pk;
    pk.x = pack_h2(hreg[0], hreg[1]);
    pk.y = pack_h2(hreg[2], hreg[3]);
    *(uint2*)(nb + nd*32 + ((8*w + 2*g) ^ swz)) = pk;

    __syncthreads();
  }

  // ---- Phase C: fused linear head ----
  float* hs = (float*)hb;
  #pragma unroll
  for(int i=0;i<4;i++) hs[nd*64 + chB + g*4 + i] = hreg[i];
  __syncthreads();
  if(tid < 16*P){
    int ndl = tid & 15, p = tid >> 4;
    int node2 = nbase + ndl;
    if(node2 < N){
      float acc = lin_b[p];
      const float* hrow = hs + ndl*64;
      #pragma unroll
      for(int q=0;q<16;q++){
        float4 v = *(const float4*)(hrow + q*4);
        float4 lw = *(const float4*)(lin_w + p*HH + q*4);
        acc += v.x*lw.x + v.y*lw.y + v.z*lw.z + v.w*lw.w;
      }
      out[(size_t)p*N + node2] = acc;
    }
  }
}

extern "C" void kernel_launch(void* const* d_in, const int* in_sizes, int n_in,
                              void* d_out, int out_size, void* d_ws, size_t ws_size,
                              hipStream_t stream){
  const float* x     = (const float*)d_in[0];
  const float* gcn_w = (const float*)d_in[2];
  const float* gcn_b = (const float*)d_in[3];
  const float* w_ih  = (const float*)d_in[4];
  const float* w_hh  = (const float*)d_in[5];
  const float* b_ih  = (const float*)d_in[6];
  const float* b_hh  = (const float*)d_in[7];
  const float* lin_w = (const float*)d_in[8];
  const float* lin_b = (const float*)d_in[9];
  const int*   ei    = (const int*)d_in[10];
  const int E = in_sizes[10]/2;
  const int N = in_sizes[0]/(TT*FF);
  const int P = in_sizes[9];

  char* wsp = (char*)d_ws;
  auto alloc = [&](size_t bytes)->void*{ void* p = wsp; wsp += (bytes + 255) & ~(size_t)255; return p; };
  int*    cnt      = (int*)   alloc((size_t)N*4);
  ushort* ell      = (ushort*)alloc((size_t)N*ELLW*2);
  ushort* xTh      = (ushort*)alloc((size_t)N*384*2);
  ushort* m1F      = (ushort*)alloc((size_t)GG*FF*2);
  float*  c1       = (float*) alloc((size_t)GG*4);
  ushort* whhF     = (ushort*)alloc((size_t)GG*HH*2);

  hipMemsetAsync(cnt, 0, (size_t)N*4, stream);

  const int GX = (N + 15)/16;
  const int GD = (E + 255)/256;
  const int GP = (GG*HH + 255)/256;
  k_pre2 <<<GX + GD + GP, 256, 0, stream>>>(x, xTh, ei, E, cnt, ell,
                                            gcn_w, gcn_b, w_ih, b_ih, w_hh,
                                            m1F, c1, whhF, N, GX, GD);
  k_fused<<<(N+15)/16, 256, 0, stream>>>(xTh, cnt, ell, whhF, m1F, c1, b_hh,
                                         lin_w, lin_b, (float*)d_out, N, P);
}

// Round 20
// 378.298 us; speedup vs baseline: 1.5569x; 1.5569x over previous
//
#include <hip/hip_runtime.h>
#include <hip/hip_bf16.h>
#include <hip/hip_fp16.h>

#define TT 24
#define FF 16
#define HH 64
#define GG 192   // 3*HH
#define ELLW 96  // ELL stride; Poisson(32) max deg ~66 << 96
#define AROW 396 // agg_lds row stride (198 dwords == 6 mod 32 -> conflict-free b128)

typedef __attribute__((ext_vector_type(4))) float f32x4;
typedef __attribute__((ext_vector_type(8))) _Float16 f16x8;

__device__ __forceinline__ float fast_rcp(float x){ return __builtin_amdgcn_rcpf(x); }
__device__ __forceinline__ float sigmoid_f(float x){
  return fast_rcp(1.0f + __expf(-x));
}
__device__ __forceinline__ float tanh_f(float x){
  float e = __expf(-2.0f * fabsf(x));
  float th = (1.0f - e) * fast_rcp(1.0f + e);
  return copysignf(th, x);
}
__device__ __forceinline__ uint pack_h2(float a, float b){
  ushort ha = __half_as_ushort(__float2half(a));
  ushort hb = __half_as_ushort(__float2half(b));
  return (uint)ha | ((uint)hb << 16);
}
__device__ __forceinline__ void acc8(float* a, uint4 u, float w){
  __half2 p0 = *(__half2*)&u.x, p1 = *(__half2*)&u.y;
  __half2 p2 = *(__half2*)&u.z, p3 = *(__half2*)&u.w;
  float2 f0 = __half22float2(p0), f1 = __half22float2(p1);
  float2 f2 = __half22float2(p2), f3 = __half22float2(p3);
  a[0] += w*f0.x; a[1] += w*f0.y; a[2] += w*f1.x; a[3] += w*f1.y;
  a[4] += w*f2.x; a[5] += w*f2.y; a[6] += w*f3.x; a[7] += w*f3.y;
}
__device__ __forceinline__ void acc4(float* a, uint2 u, float w){
  __half2 p0 = *(__half2*)&u.x, p1 = *(__half2*)&u.y;
  float2 f0 = __half22float2(p0), f1 = __half22float2(p1);
  a[0] += w*f0.x; a[1] += w*f0.y; a[2] += w*f1.x; a[3] += w*f1.y;
}

// ---------------- fused prologue: xt2 || ELL-fill (ushort) || prep ----------------
__global__ __launch_bounds__(256)
void k_pre2(const float* __restrict__ x, ushort* __restrict__ xTh,
            const int* __restrict__ ei, int E, int* __restrict__ cnt, ushort* __restrict__ ell,
            const float* __restrict__ gcn_w, const float* __restrict__ gcn_b,
            const float* __restrict__ w_ih, const float* __restrict__ b_ih,
            const float* __restrict__ w_hh,
            ushort* __restrict__ m1F, float* __restrict__ c1, ushort* __restrict__ whhF,
            int N, int GX, int GD){
  __shared__ ushort tile[16][392];
  const int bid = blockIdx.x;
  const int tid = threadIdx.x;
  if(bid < GX){
    const int nbase = bid * 16;
    const int nd = tid >> 4, f = tid & 15;
    const int n = nbase + nd;
    for(int t=0; t<TT; t++){
      float v = (n < N) ? x[((size_t)t*N + n)*FF + f] : 0.f;
      tile[nd][t*16 + f] = __half_as_ushort(__float2half(v));
    }
    __syncthreads();
    uint* xo = (uint*)xTh;
    for(int i = tid; i < 16*192; i += 256){
      int d = i / 192, pos = i - d*192;
      int nn = nbase + d;
      if(nn < N) xo[(size_t)nn*192 + pos] = *(uint*)&tile[d][pos*2];
    }
  } else if(bid < GX + GD){
    // single-pass ELL build: cnt doubles as degree
    int i = (bid - GX)*256 + tid;
    if(i < E){
      int s = ei[i], d = ei[E+i];
      int slot = atomicAdd(&cnt[d], 1);
      if(slot < ELLW) ell[(size_t)d*ELLW + slot] = (ushort)s;
    }
  } else {
    int t2 = (bid - GX - GD)*256 + tid;
    if(t2 < GG*FF){
      int j = t2 >> 4, f = t2 & 15;
      float s = 0.f;
      for(int k=0;k<HH;k++) s += gcn_w[f*HH+k]*w_ih[j*HH+k];
      m1F[t2] = __half_as_ushort(__float2half(s));
    } else if (t2 < GG*FF + GG){
      int j = t2 - GG*FF;
      float s = b_ih[j];
      for(int k=0;k<HH;k++) s += gcn_b[k]*w_ih[j*HH+k];
      c1[j] = s;
    }
    if(t2 < GG*HH){
      whhF[t2] = __half_as_ushort(__float2half(w_hh[t2]));
    }
  }
}

// ---------------- fused agg + GRU + head: block = 16 nodes, 4 waves ----------------
__global__ __launch_bounds__(256, 6)
void k_fused(const ushort* __restrict__ xTh, const int* __restrict__ cnt,
             const ushort* __restrict__ ell,
             const ushort* __restrict__ whhF, const ushort* __restrict__ m1F,
             const float* __restrict__ c1, const float* __restrict__ bhh,
             const float* __restrict__ lin_w, const float* __restrict__ lin_b,
             float* __restrict__ out, int N, int P){
  __shared__ __align__(16) ushort agg_lds[16][AROW];  // pos = t*16+f, stride conflict-free
  __shared__ __align__(16) uint hb[2][512];           // 4 KB h dbuf (f16)
  const int tid = threadIdx.x;
  const int l = tid & 63, w = tid >> 6;
  const int half = l >> 5, lh = l & 31;
  const int nbase = blockIdx.x * 16;

  // zero h buffer 0 (covered by the phase-A barrier)
  for(int i=tid; i<512; i+=256) hb[0][i]=0u;

  // ---- Phase A: aggregation, 4 nodes per wave ----
  for(int q=0; q<4; q++){
    const int nl = w*4 + q;
    const int n = min(nbase + nl, N-1);
    float aA[8] = {0.f,0.f,0.f,0.f,0.f,0.f,0.f,0.f};
    float aB[4] = {0.f,0.f,0.f,0.f};
    const int cn = cnt[n];
    const float dn = rsqrtf((float)cn + 1.0f);
    const int hi = min(cn, ELLW);
    const ushort* eb = ell + (size_t)n*ELLW;

    for(int j = 0; j < hi; j += 8){
      int j0 = j     + half;
      int j1 = j + 2 + half;
      int j2 = j + 4 + half;
      int j3 = j + 6 + half;
      bool k0 = j0 < hi, k1 = j1 < hi, k2 = j2 < hi, k3 = j3 < hi;
      int s0 = n, s1 = n, s2 = n, s3 = n;
      if(k0) s0 = eb[j0];
      if(k1) s1 = eb[j1];
      if(k2) s2 = eb[j2];
      if(k3) s3 = eb[j3];
      float w0 = k0 ? rsqrtf((float)cnt[s0] + 1.0f)*dn : 0.f;
      float w1 = k1 ? rsqrtf((float)cnt[s1] + 1.0f)*dn : 0.f;
      float w2 = k2 ? rsqrtf((float)cnt[s2] + 1.0f)*dn : 0.f;
      float w3 = k3 ? rsqrtf((float)cnt[s3] + 1.0f)*dn : 0.f;
      const ushort* r0 = xTh + (size_t)s0*384;
      const ushort* r1 = xTh + (size_t)s1*384;
      const ushort* r2 = xTh + (size_t)s2*384;
      const ushort* r3 = xTh + (size_t)s3*384;
      uint4 A0 = *(const uint4*)(r0 + lh*8);
      uint4 A1 = *(const uint4*)(r1 + lh*8);
      uint4 A2 = *(const uint4*)(r2 + lh*8);
      uint4 A3 = *(const uint4*)(r3 + lh*8);
      uint2 B0 = *(const uint2*)(r0 + 256 + lh*4);
      uint2 B1 = *(const uint2*)(r1 + 256 + lh*4);
      uint2 B2 = *(const uint2*)(r2 + 256 + lh*4);
      uint2 B3 = *(const uint2*)(r3 + 256 + lh*4);
      acc8(aA, A0, w0); acc4(aB, B0, w0);
      acc8(aA, A1, w1); acc4(aB, B1, w1);
      acc8(aA, A2, w2); acc4(aB, B2, w2);
      acc8(aA, A3, w3); acc4(aB, B3, w3);
    }
    #pragma unroll
    for(int k=0;k<8;k++) aA[k] += __shfl_xor(aA[k], 32, 64);
    #pragma unroll
    for(int k=0;k<4;k++) aB[k] += __shfl_xor(aB[k], 32, 64);

    if(half == 0){
      float sn = dn*dn;
      const ushort* rS = xTh + (size_t)n*384;
      uint4 AS = *(const uint4*)(rS + lh*8);
      uint2 BS = *(const uint2*)(rS + 256 + lh*4);
      acc8(aA, AS, sn); acc4(aB, BS, sn);
      ushort* row = &agg_lds[nl][0];
      uint4 h0;
      h0.x = pack_h2(aA[0], aA[1]);
      h0.y = pack_h2(aA[2], aA[3]);
      h0.z = pack_h2(aA[4], aA[5]);
      h0.w = pack_h2(aA[6], aA[7]);
      *(uint4*)(row + lh*8) = h0;
      uint2 hB;
      hB.x = pack_h2(aB[0], aB[1]);
      hB.y = pack_h2(aB[2], aB[3]);
      *(uint2*)(row + 256 + lh*4) = hB;
    }
  }
  __syncthreads();

  // ---- Phase B: GRU ----
  const int nd = l & 15, g = l >> 4;
  const int chB = 16*w;
  const f16x8 zf = (f16x8){0,0,0,0,0,0,0,0};
  f16x8 ar0,ar1,az0,az1,an0,an1, mr,mz,mn;
  {
    const int rr =        chB + nd;
    const int rz =  HH  + chB + nd;
    const int rn = 2*HH + chB + nd;
    ar0 = *(const f16x8*)(whhF + rr*HH      + g*8);
    ar1 = *(const f16x8*)(whhF + rr*HH + 32 + g*8);
    az0 = *(const f16x8*)(whhF + rz*HH      + g*8);
    az1 = *(const f16x8*)(whhF + rz*HH + 32 + g*8);
    an0 = *(const f16x8*)(whhF + rn*HH      + g*8);
    an1 = *(const f16x8*)(whhF + rn*HH + 32 + g*8);
    mr = zf; mz = zf; mn = zf;
    if(g < 2){
      mr = *(const f16x8*)(m1F + rr*FF + g*8);
      mz = *(const f16x8*)(m1F + rz*FF + g*8);
      mn = *(const f16x8*)(m1F + rn*FF + g*8);
    } else if(g == 2){
      mr[0] = (_Float16)(c1[rr] + bhh[rr]);
      mz[0] = (_Float16)(c1[rz] + bhh[rz]);
      mn[0] = (_Float16)(c1[rn]);
    }
  }
  float4 bb = *(const float4*)(bhh + 2*HH + chB + g*4);

  float hreg[4] = {0.f,0.f,0.f,0.f};
  f16x8 cB = zf;            // bias/zero frag for g>=2
  if(g==2) cB[0] = (_Float16)1.0f;

  const int swz = (nd & 7) << 2;

  for(int t=0; t<TT; t++){
    const uint* cb = hb[t & 1];
    uint* nb = hb[(t & 1) ^ 1];

    f16x8 hB0 = *(const f16x8*)(cb + nd*32 + ((g*4)      ^ swz));
    f16x8 hB1 = *(const f16x8*)(cb + nd*32 + ((16 + g*4) ^ swz));
    f16x8 cAg = cB;
    if(g < 2) cAg = *(const f16x8*)&agg_lds[nd][t*16 + g*8];

    f32x4 R  = {0.f,0.f,0.f,0.f};
    f32x4 Z  = {0.f,0.f,0.f,0.f};
    f32x4 Nh = {0.f,0.f,0.f,0.f};
    f32x4 Ni = {0.f,0.f,0.f,0.f};
    R  = __builtin_amdgcn_mfma_f32_16x16x32_f16(ar0, hB0, R , 0,0,0);
    R  = __builtin_amdgcn_mfma_f32_16x16x32_f16(ar1, hB1, R , 0,0,0);
    R  = __builtin_amdgcn_mfma_f32_16x16x32_f16(mr,  cAg, R , 0,0,0);
    Z  = __builtin_amdgcn_mfma_f32_16x16x32_f16(az0, hB0, Z , 0,0,0);
    Z  = __builtin_amdgcn_mfma_f32_16x16x32_f16(az1, hB1, Z , 0,0,0);
    Z  = __builtin_amdgcn_mfma_f32_16x16x32_f16(mz,  cAg, Z , 0,0,0);
    Nh = __builtin_amdgcn_mfma_f32_16x16x32_f16(an0, hB0, Nh, 0,0,0);
    Nh = __builtin_amdgcn_mfma_f32_16x16x32_f16(an1, hB1, Nh, 0,0,0);
    Ni = __builtin_amdgcn_mfma_f32_16x16x32_f16(mn,  cAg, Ni, 0,0,0);

    const float bbv[4] = {bb.x, bb.y, bb.z, bb.w};
    #pragma unroll
    for(int i=0;i<4;i++){
      float r_ = sigmoid_f(R[i]);
      float z_ = sigmoid_f(Z[i]);
      float nn = tanh_f(Ni[i] + r_*(Nh[i] + bbv[i]));
      hreg[i] = nn + z_*(hreg[i] - nn);
    }
    uint2 pk;
    pk.x = pack_h2(hreg[0], hreg[1]);
    pk.y = pack_h2(hreg[2], hreg[3]);
    *(uint2*)(nb + nd*32 + ((8*w + 2*g) ^ swz)) = pk;

    __syncthreads();
  }

  // ---- Phase C: fused linear head ----
  float* hs = (float*)hb;
  #pragma unroll
  for(int i=0;i<4;i++) hs[nd*64 + chB + g*4 + i] = hreg[i];
  __syncthreads();
  if(tid < 16*P){
    int ndl = tid & 15, p = tid >> 4;
    int node2 = nbase + ndl;
    if(node2 < N){
      float acc = lin_b[p];
      const float* hrow = hs + ndl*64;
      #pragma unroll
      for(int q=0;q<16;q++){
        float4 v = *(const float4*)(hrow + q*4);
        float4 lw = *(const float4*)(lin_w + p*HH + q*4);
        acc += v.x*lw.x + v.y*lw.y + v.z*lw.z + v.w*lw.w;
      }
      out[(size_t)p*N + node2] = acc;
    }
  }
}

extern "C" void kernel_launch(void* const* d_in, const int* in_sizes, int n_in,
                              void* d_out, int out_size, void* d_ws, size_t ws_size,
                              hipStream_t stream){
  const float* x     = (const float*)d_in[0];
  const float* gcn_w = (const float*)d_in[2];
  const float* gcn_b = (const float*)d_in[3];
  const float* w_ih  = (const float*)d_in[4];
  const float* w_hh  = (const float*)d_in[5];
  const float* b_ih  = (const float*)d_in[6];
  const float* b_hh  = (const float*)d_in[7];
  const float* lin_w = (const float*)d_in[8];
  const float* lin_b = (const float*)d_in[9];
  const int*   ei    = (const int*)d_in[10];
  const int E = in_sizes[10]/2;
  const int N = in_sizes[0]/(TT*FF);
  const int P = in_sizes[9];

  char* wsp = (char*)d_ws;
  auto alloc = [&](size_t bytes)->void*{ void* p = wsp; wsp += (bytes + 255) & ~(size_t)255; return p; };
  int*    cnt      = (int*)   alloc((size_t)N*4);
  ushort* ell      = (ushort*)alloc((size_t)N*ELLW*2);
  ushort* xTh      = (ushort*)alloc((size_t)N*384*2);
  ushort* m1F      = (ushort*)alloc((size_t)GG*FF*2);
  float*  c1       = (float*) alloc((size_t)GG*4);
  ushort* whhF     = (ushort*)alloc((size_t)GG*HH*2);

  hipMemsetAsync(cnt, 0, (size_t)N*4, stream);

  const int GX = (N + 15)/16;
  const int GD = (E + 255)/256;
  const int GP = (GG*HH + 255)/256;
  k_pre2 <<<GX + GD + GP, 256, 0, stream>>>(x, xTh, ei, E, cnt, ell,
                                            gcn_w, gcn_b, w_ih, b_ih, w_hh,
                                            m1F, c1, whhF, N, GX, GD);
  k_fused<<<(N+15)/16, 256, 0, stream>>>(xTh, cnt, ell, whhF, m1F, c1, b_hh,
                                         lin_w, lin_b, (float*)d_out, N, P);
}

// Round 21
// 355.142 us; speedup vs baseline: 1.6584x; 1.0652x over previous
//
#include <hip/hip_runtime.h>
#include <hip/hip_bf16.h>
#include <hip/hip_fp16.h>

#define TT 24
#define FF 16
#define HH 64
#define GG 192   // 3*HH
#define ELLW 96  // ELL stride; Poisson(32) max deg ~66 << 96
#define AROW 396 // agg_lds row stride

typedef __attribute__((ext_vector_type(4))) float f32x4;
typedef __attribute__((ext_vector_type(8))) _Float16 f16x8;

__device__ __forceinline__ float fast_rcp(float x){ return __builtin_amdgcn_rcpf(x); }
__device__ __forceinline__ float sigmoid_f(float x){
  return fast_rcp(1.0f + __expf(-x));
}
__device__ __forceinline__ float tanh_f(float x){
  float e = __expf(-2.0f * fabsf(x));
  float th = (1.0f - e) * fast_rcp(1.0f + e);
  return copysignf(th, x);
}
__device__ __forceinline__ uint pack_h2(float a, float b){
  ushort ha = __half_as_ushort(__float2half(a));
  ushort hb = __half_as_ushort(__float2half(b));
  return (uint)ha | ((uint)hb << 16);
}
__device__ __forceinline__ void acc8(float* a, uint4 u, float w){
  __half2 p0 = *(__half2*)&u.x, p1 = *(__half2*)&u.y;
  __half2 p2 = *(__half2*)&u.z, p3 = *(__half2*)&u.w;
  float2 f0 = __half22float2(p0), f1 = __half22float2(p1);
  float2 f2 = __half22float2(p2), f3 = __half22float2(p3);
  a[0] += w*f0.x; a[1] += w*f0.y; a[2] += w*f1.x; a[3] += w*f1.y;
  a[4] += w*f2.x; a[5] += w*f2.y; a[6] += w*f3.x; a[7] += w*f3.y;
}
__device__ __forceinline__ void acc4(float* a, uint2 u, float w){
  __half2 p0 = *(__half2*)&u.x, p1 = *(__half2*)&u.y;
  float2 f0 = __half22float2(p0), f1 = __half22float2(p1);
  a[0] += w*f0.x; a[1] += w*f0.y; a[2] += w*f1.x; a[3] += w*f1.y;
}

// ---------------- fused prologue: xt2 || ELL-fill (ushort) || prep ----------------
__global__ __launch_bounds__(256)
void k_pre2(const float* __restrict__ x, ushort* __restrict__ xTh,
            const int* __restrict__ ei, int E, int* __restrict__ cnt, ushort* __restrict__ ell,
            const float* __restrict__ gcn_w, const float* __restrict__ gcn_b,
            const float* __restrict__ w_ih, const float* __restrict__ b_ih,
            const float* __restrict__ w_hh,
            ushort* __restrict__ m1F, float* __restrict__ c1, ushort* __restrict__ whhF,
            int N, int GX, int GD){
  __shared__ ushort tile[16][392];
  const int bid = blockIdx.x;
  const int tid = threadIdx.x;
  if(bid < GX){
    const int nbase = bid * 16;
    const int nd = tid >> 4, f = tid & 15;
    const int n = nbase + nd;
    for(int t=0; t<TT; t++){
      float v = (n < N) ? x[((size_t)t*N + n)*FF + f] : 0.f;
      tile[nd][t*16 + f] = __half_as_ushort(__float2half(v));
    }
    __syncthreads();
    uint* xo = (uint*)xTh;
    for(int i = tid; i < 16*192; i += 256){
      int d = i / 192, pos = i - d*192;
      int nn = nbase + d;
      if(nn < N) xo[(size_t)nn*192 + pos] = *(uint*)&tile[d][pos*2];
    }
  } else if(bid < GX + GD){
    // single-pass ELL build: cnt doubles as degree
    int i = (bid - GX)*256 + tid;
    if(i < E){
      int s = ei[i], d = ei[E+i];
      int slot = atomicAdd(&cnt[d], 1);
      if(slot < ELLW) ell[(size_t)d*ELLW + slot] = (ushort)s;
    }
  } else {
    int t2 = (bid - GX - GD)*256 + tid;
    if(t2 < GG*FF){
      int j = t2 >> 4, f = t2 & 15;
      float s = 0.f;
      for(int k=0;k<HH;k++) s += gcn_w[f*HH+k]*w_ih[j*HH+k];
      m1F[t2] = __half_as_ushort(__float2half(s));
    } else if (t2 < GG*FF + GG){
      int j = t2 - GG*FF;
      float s = b_ih[j];
      for(int k=0;k<HH;k++) s += gcn_b[k]*w_ih[j*HH+k];
      c1[j] = s;
    }
    if(t2 < GG*HH){
      whhF[t2] = __half_as_ushort(__float2half(w_hh[t2]));
    }
  }
}

// ---------------- fused agg + GRU + head: block = 16 nodes, 4 waves ----------------
__global__ __launch_bounds__(256, 4)
void k_fused(const ushort* __restrict__ xTh, const int* __restrict__ cnt,
             const ushort* __restrict__ ell,
             const ushort* __restrict__ whhF, const ushort* __restrict__ m1F,
             const float* __restrict__ c1, const float* __restrict__ bhh,
             const float* __restrict__ lin_w, const float* __restrict__ lin_b,
             float* __restrict__ out, int N, int P){
  __shared__ __align__(16) ushort agg_lds[16][AROW];  // pos = t*16+f
  __shared__ __align__(16) uint hb[2][512];           // 4 KB h dbuf (f16)
  __shared__ __align__(16) uint ell_w[4][48];         // per-wave staged ELL row (96 ushorts)
  const int tid = threadIdx.x;
  const int l = tid & 63, w = tid >> 6;
  const int half = l >> 5, lh = l & 31;
  const int nbase = blockIdx.x * 16;

  // zero h buffer 0 (covered by the phase-A barrier)
  for(int i=tid; i<512; i+=256) hb[0][i]=0u;

  // ---- Phase A: aggregation, 4 nodes per wave; ELL row staged in LDS ----
  const ushort* myell = (const ushort*)ell_w[w];
  for(int q=0; q<4; q++){
    const int nl = w*4 + q;
    const int n = min(nbase + nl, N-1);
    float aA[8] = {0.f,0.f,0.f,0.f,0.f,0.f,0.f,0.f};
    float aB[4] = {0.f,0.f,0.f,0.f};
    const int cn = cnt[n];
    const float dn = rsqrtf((float)cn + 1.0f);
    const int hi = min(cn, ELLW);

    // stage the 96-entry row (48 dwords) into wave-private LDS, coalesced
    if(l < 48) ell_w[w][l] = *(const uint*)(ell + (size_t)n*ELLW + l*2);
    // same-wave LDS in-order: reads below wait on lgkmcnt automatically

    for(int j = 0; j < hi; j += 8){
      int j0 = j     + half;
      int j1 = j + 2 + half;
      int j2 = j + 4 + half;
      int j3 = j + 6 + half;
      bool k0 = j0 < hi, k1 = j1 < hi, k2 = j2 < hi, k3 = j3 < hi;
      int s0 = n, s1 = n, s2 = n, s3 = n;
      if(k0) s0 = myell[j0];
      if(k1) s1 = myell[j1];
      if(k2) s2 = myell[j2];
      if(k3) s3 = myell[j3];
      float w0 = k0 ? rsqrtf((float)cnt[s0] + 1.0f)*dn : 0.f;
      float w1 = k1 ? rsqrtf((float)cnt[s1] + 1.0f)*dn : 0.f;
      float w2 = k2 ? rsqrtf((float)cnt[s2] + 1.0f)*dn : 0.f;
      float w3 = k3 ? rsqrtf((float)cnt[s3] + 1.0f)*dn : 0.f;
      const ushort* r0 = xTh + (size_t)s0*384;
      const ushort* r1 = xTh + (size_t)s1*384;
      const ushort* r2 = xTh + (size_t)s2*384;
      const ushort* r3 = xTh + (size_t)s3*384;
      uint4 A0 = *(const uint4*)(r0 + lh*8);
      uint4 A1 = *(const uint4*)(r1 + lh*8);
      uint4 A2 = *(const uint4*)(r2 + lh*8);
      uint4 A3 = *(const uint4*)(r3 + lh*8);
      uint2 B0 = *(const uint2*)(r0 + 256 + lh*4);
      uint2 B1 = *(const uint2*)(r1 + 256 + lh*4);
      uint2 B2 = *(const uint2*)(r2 + 256 + lh*4);
      uint2 B3 = *(const uint2*)(r3 + 256 + lh*4);
      acc8(aA, A0, w0); acc4(aB, B0, w0);
      acc8(aA, A1, w1); acc4(aB, B1, w1);
      acc8(aA, A2, w2); acc4(aB, B2, w2);
      acc8(aA, A3, w3); acc4(aB, B3, w3);
    }
    #pragma unroll
    for(int k=0;k<8;k++) aA[k] += __shfl_xor(aA[k], 32, 64);
    #pragma unroll
    for(int k=0;k<4;k++) aB[k] += __shfl_xor(aB[k], 32, 64);

    if(half == 0){
      float sn = dn*dn;
      const ushort* rS = xTh + (size_t)n*384;
      uint4 AS = *(const uint4*)(rS + lh*8);
      uint2 BS = *(const uint2*)(rS + 256 + lh*4);
      acc8(aA, AS, sn); acc4(aB, BS, sn);
      ushort* row = &agg_lds[nl][0];
      uint4 h0;
      h0.x = pack_h2(aA[0], aA[1]);
      h0.y = pack_h2(aA[2], aA[3]);
      h0.z = pack_h2(aA[4], aA[5]);
      h0.w = pack_h2(aA[6], aA[7]);
      *(uint4*)(row + lh*8) = h0;
      uint2 hB;
      hB.x = pack_h2(aB[0], aB[1]);
      hB.y = pack_h2(aB[2], aB[3]);
      *(uint2*)(row + 256 + lh*4) = hB;
    }
  }
  __syncthreads();

  // ---- Phase B: GRU ----
  const int nd = l & 15, g = l >> 4;
  const int chB = 16*w;
  const f16x8 zf = (f16x8){0,0,0,0,0,0,0,0};
  f16x8 ar0,ar1,az0,az1,an0,an1, mr,mz,mn;
  {
    const int rr =        chB + nd;
    const int rz =  HH  + chB + nd;
    const int rn = 2*HH + chB + nd;
    ar0 = *(const f16x8*)(whhF + rr*HH      + g*8);
    ar1 = *(const f16x8*)(whhF + rr*HH + 32 + g*8);
    az0 = *(const f16x8*)(whhF + rz*HH      + g*8);
    az1 = *(const f16x8*)(whhF + rz*HH + 32 + g*8);
    an0 = *(const f16x8*)(whhF + rn*HH      + g*8);
    an1 = *(const f16x8*)(whhF + rn*HH + 32 + g*8);
    mr = zf; mz = zf; mn = zf;
    if(g < 2){
      mr = *(const f16x8*)(m1F + rr*FF + g*8);
      mz = *(const f16x8*)(m1F + rz*FF + g*8);
      mn = *(const f16x8*)(m1F + rn*FF + g*8);
    } else if(g == 2){
      mr[0] = (_Float16)(c1[rr] + bhh[rr]);
      mz[0] = (_Float16)(c1[rz] + bhh[rz]);
      mn[0] = (_Float16)(c1[rn]);
    }
  }
  float4 bb = *(const float4*)(bhh + 2*HH + chB + g*4);

  float hreg[4] = {0.f,0.f,0.f,0.f};
  f16x8 cB = zf;            // bias/zero frag for g>=2
  if(g==2) cB[0] = (_Float16)1.0f;

  const int swz = (nd & 7) << 2;

  for(int t=0; t<TT; t++){
    const uint* cb = hb[t & 1];
    uint* nb = hb[(t & 1) ^ 1];

    f16x8 hB0 = *(const f16x8*)(cb + nd*32 + ((g*4)      ^ swz));
    f16x8 hB1 = *(const f16x8*)(cb + nd*32 + ((16 + g*4) ^ swz));
    f16x8 cAg = cB;
    if(g < 2) cAg = *(const f16x8*)&agg_lds[nd][t*16 + g*8];

    f32x4 R  = {0.f,0.f,0.f,0.f};
    f32x4 Z  = {0.f,0.f,0.f,0.f};
    f32x4 Nh = {0.f,0.f,0.f,0.f};
    f32x4 Ni = {0.f,0.f,0.f,0.f};
    R  = __builtin_amdgcn_mfma_f32_16x16x32_f16(ar0, hB0, R , 0,0,0);
    R  = __builtin_amdgcn_mfma_f32_16x16x32_f16(ar1, hB1, R , 0,0,0);
    R  = __builtin_amdgcn_mfma_f32_16x16x32_f16(mr,  cAg, R , 0,0,0);
    Z  = __builtin_amdgcn_mfma_f32_16x16x32_f16(az0, hB0, Z , 0,0,0);
    Z  = __builtin_amdgcn_mfma_f32_16x16x32_f16(az1, hB1, Z , 0,0,0);
    Z  = __builtin_amdgcn_mfma_f32_16x16x32_f16(mz,  cAg, Z , 0,0,0);
    Nh = __builtin_amdgcn_mfma_f32_16x16x32_f16(an0, hB0, Nh, 0,0,0);
    Nh = __builtin_amdgcn_mfma_f32_16x16x32_f16(an1, hB1, Nh, 0,0,0);
    Ni = __builtin_amdgcn_mfma_f32_16x16x32_f16(mn,  cAg, Ni, 0,0,0);

    const float bbv[4] = {bb.x, bb.y, bb.z, bb.w};
    #pragma unroll
    for(int i=0;i<4;i++){
      float r_ = sigmoid_f(R[i]);
      float z_ = sigmoid_f(Z[i]);
      float nn = tanh_f(Ni[i] + r_*(Nh[i] + bbv[i]));
      hreg[i] = nn + z_*(hreg[i] - nn);
    }
    uint2 pk;
    pk.x = pack_h2(hreg[0], hreg[1]);
    pk.y = pack_h2(hreg[2], hreg[3]);
    *(uint2*)(nb + nd*32 + ((8*w + 2*g) ^ swz)) = pk;

    __syncthreads();
  }

  // ---- Phase C: fused linear head ----
  float* hs = (float*)hb;
  #pragma unroll
  for(int i=0;i<4;i++) hs[nd*64 + chB + g*4 + i] = hreg[i];
  __syncthreads();
  if(tid < 16*P){
    int ndl = tid & 15, p = tid >> 4;
    int node2 = nbase + ndl;
    if(node2 < N){
      float acc = lin_b[p];
      const float* hrow = hs + ndl*64;
      #pragma unroll
      for(int q=0;q<16;q++){
        float4 v = *(const float4*)(hrow + q*4);
        float4 lw = *(const float4*)(lin_w + p*HH + q*4);
        acc += v.x*lw.x + v.y*lw.y + v.z*lw.z + v.w*lw.w;
      }
      out[(size_t)p*N + node2] = acc;
    }
  }
}

extern "C" void kernel_launch(void* const* d_in, const int* in_sizes, int n_in,
                              void* d_out, int out_size, void* d_ws, size_t ws_size,
                              hipStream_t stream){
  const float* x     = (const float*)d_in[0];
  const float* gcn_w = (const float*)d_in[2];
  const float* gcn_b = (const float*)d_in[3];
  const float* w_ih  = (const float*)d_in[4];
  const float* w_hh  = (const float*)d_in[5];
  const float* b_ih  = (const float*)d_in[6];
  const float* b_hh  = (const float*)d_in[7];
  const float* lin_w = (const float*)d_in[8];
  const float* lin_b = (const float*)d_in[9];
  const int*   ei    = (const int*)d_in[10];
  const int E = in_sizes[10]/2;
  const int N = in_sizes[0]/(TT*FF);
  const int P = in_sizes[9];

  char* wsp = (char*)d_ws;
  auto alloc = [&](size_t bytes)->void*{ void* p = wsp; wsp += (bytes + 255) & ~(size_t)255; return p; };
  int*    cnt      = (int*)   alloc((size_t)N*4);
  ushort* ell      = (ushort*)alloc((size_t)N*ELLW*2);
  ushort* xTh      = (ushort*)alloc((size_t)N*384*2);
  ushort* m1F      = (ushort*)alloc((size_t)GG*FF*2);
  float*  c1       = (float*) alloc((size_t)GG*4);
  ushort* whhF     = (ushort*)alloc((size_t)GG*HH*2);

  hipMemsetAsync(cnt, 0, (size_t)N*4, stream);

  const int GX = (N + 15)/16;
  const int GD = (E + 255)/256;
  const int GP = (GG*HH + 255)/256;
  k_pre2 <<<GX + GD + GP, 256, 0, stream>>>(x, xTh, ei, E, cnt, ell,
                                            gcn_w, gcn_b, w_ih, b_ih, w_hh,
                                            m1F, c1, whhF, N, GX, GD);
  k_fused<<<(N+15)/16, 256, 0, stream>>>(xTh, cnt, ell, whhF, m1F, c1, b_hh,
                                         lin_w, lin_b, (float*)d_out, N, P);
}

// Round 22
// 345.860 us; speedup vs baseline: 1.7030x; 1.0268x over previous
//
#include <hip/hip_runtime.h>
#include <hip/hip_bf16.h>
#include <hip/hip_fp16.h>

#define TT 24
#define FF 16
#define HH 64
#define GG 192   // 3*HH
#define ELLW 96  // ELL stride; Poisson(32) max deg ~66 << 96
#define AROW 396 // agg_lds row stride

typedef __attribute__((ext_vector_type(4))) float f32x4;
typedef __attribute__((ext_vector_type(8))) _Float16 f16x8;

__device__ __forceinline__ float fast_rcp(float x){ return __builtin_amdgcn_rcpf(x); }
__device__ __forceinline__ float sigmoid_f(float x){
  return fast_rcp(1.0f + __expf(-x));
}
__device__ __forceinline__ float tanh_f(float x){
  float e = __expf(-2.0f * fabsf(x));
  float th = (1.0f - e) * fast_rcp(1.0f + e);
  return copysignf(th, x);
}
__device__ __forceinline__ uint pack_h2(float a, float b){
  ushort ha = __half_as_ushort(__float2half(a));
  ushort hb = __half_as_ushort(__float2half(b));
  return (uint)ha | ((uint)hb << 16);
}
__device__ __forceinline__ void acch8(__half2* a, uint4 u, __half2 wh){
  a[0] = __hfma2(*(__half2*)&u.x, wh, a[0]);
  a[1] = __hfma2(*(__half2*)&u.y, wh, a[1]);
  a[2] = __hfma2(*(__half2*)&u.z, wh, a[2]);
  a[3] = __hfma2(*(__half2*)&u.w, wh, a[3]);
}
__device__ __forceinline__ void acch4(__half2* a, uint2 u, __half2 wh){
  a[0] = __hfma2(*(__half2*)&u.x, wh, a[0]);
  a[1] = __hfma2(*(__half2*)&u.y, wh, a[1]);
}

// ---------------- fused prologue: xt2 || ELL-fill (ushort) || prep ----------------
__global__ __launch_bounds__(256)
void k_pre2(const float* __restrict__ x, ushort* __restrict__ xTh,
            const int* __restrict__ ei, int E, int* __restrict__ cnt, ushort* __restrict__ ell,
            const float* __restrict__ gcn_w, const float* __restrict__ gcn_b,
            const float* __restrict__ w_ih, const float* __restrict__ b_ih,
            const float* __restrict__ w_hh,
            ushort* __restrict__ m1F, float* __restrict__ c1, ushort* __restrict__ whhF,
            int N, int GX, int GD){
  __shared__ ushort tile[16][392];
  const int bid = blockIdx.x;
  const int tid = threadIdx.x;
  if(bid < GX){
    const int nbase = bid * 16;
    const int nd = tid >> 4, f = tid & 15;
    const int n = nbase + nd;
    for(int t=0; t<TT; t++){
      float v = (n < N) ? x[((size_t)t*N + n)*FF + f] : 0.f;
      tile[nd][t*16 + f] = __half_as_ushort(__float2half(v));
    }
    __syncthreads();
    uint* xo = (uint*)xTh;
    for(int i = tid; i < 16*192; i += 256){
      int d = i / 192, pos = i - d*192;
      int nn = nbase + d;
      if(nn < N) xo[(size_t)nn*192 + pos] = *(uint*)&tile[d][pos*2];
    }
  } else if(bid < GX + GD){
    // single-pass ELL build: cnt doubles as degree
    int i = (bid - GX)*256 + tid;
    if(i < E){
      int s = ei[i], d = ei[E+i];
      int slot = atomicAdd(&cnt[d], 1);
      if(slot < ELLW) ell[(size_t)d*ELLW + slot] = (ushort)s;
    }
  } else {
    int t2 = (bid - GX - GD)*256 + tid;
    if(t2 < GG*FF){
      int j = t2 >> 4, f = t2 & 15;
      float s = 0.f;
      for(int k=0;k<HH;k++) s += gcn_w[f*HH+k]*w_ih[j*HH+k];
      m1F[t2] = __half_as_ushort(__float2half(s));
    } else if (t2 < GG*FF + GG){
      int j = t2 - GG*FF;
      float s = b_ih[j];
      for(int k=0;k<HH;k++) s += gcn_b[k]*w_ih[j*HH+k];
      c1[j] = s;
    }
    if(t2 < GG*HH){
      whhF[t2] = __half_as_ushort(__float2half(w_hh[t2]));
    }
  }
}

// ---------------- fused agg + GRU + head: block = 16 nodes, 4 waves ----------------
__global__ __launch_bounds__(256, 4)
void k_fused(const ushort* __restrict__ xTh, const int* __restrict__ cnt,
             const ushort* __restrict__ ell,
             const ushort* __restrict__ whhF, const ushort* __restrict__ m1F,
             const float* __restrict__ c1, const float* __restrict__ bhh,
             const float* __restrict__ lin_w, const float* __restrict__ lin_b,
             float* __restrict__ out, int N, int P){
  __shared__ __align__(16) ushort agg_lds[16][AROW];  // pos = t*16+f
  __shared__ __align__(16) uint hb[2][512];           // 4 KB h dbuf (f16)
  __shared__ __align__(16) uint ell_w[4][48];         // per-wave staged ELL row
  const int tid = threadIdx.x;
  const int l = tid & 63, w = tid >> 6;
  const int half = l >> 5, lh = l & 31;
  const int nbase = blockIdx.x * 16;

  // zero h buffer 0 (covered by the phase-A barrier)
  for(int i=tid; i<512; i+=256) hb[0][i]=0u;

  // ---- Phase A: aggregation, 4 nodes per wave; f16 packed accumulation ----
  const ushort* myell = (const ushort*)ell_w[w];
  for(int q=0; q<4; q++){
    const int nl = w*4 + q;
    const int n = min(nbase + nl, N-1);
    __half2 hA[4], hB2[2];
    hA[0]=__half2{0,0}; hA[1]=__half2{0,0}; hA[2]=__half2{0,0}; hA[3]=__half2{0,0};
    hB2[0]=__half2{0,0}; hB2[1]=__half2{0,0};
    const int cn = cnt[n];
    const float dn = rsqrtf((float)cn + 1.0f);
    const int hi = min(cn, ELLW);

    // stage the 96-entry ELL row (48 dwords) into wave-private LDS, coalesced
    if(l < 48) ell_w[w][l] = *(const uint*)(ell + (size_t)n*ELLW + l*2);

    for(int j = 0; j < hi; j += 8){
      int j0 = j     + half;
      int j1 = j + 2 + half;
      int j2 = j + 4 + half;
      int j3 = j + 6 + half;
      bool k0 = j0 < hi, k1 = j1 < hi, k2 = j2 < hi, k3 = j3 < hi;
      int s0 = n, s1 = n, s2 = n, s3 = n;
      if(k0) s0 = myell[j0];
      if(k1) s1 = myell[j1];
      if(k2) s2 = myell[j2];
      if(k3) s3 = myell[j3];
      float w0 = k0 ? rsqrtf((float)cnt[s0] + 1.0f)*dn : 0.f;
      float w1 = k1 ? rsqrtf((float)cnt[s1] + 1.0f)*dn : 0.f;
      float w2 = k2 ? rsqrtf((float)cnt[s2] + 1.0f)*dn : 0.f;
      float w3 = k3 ? rsqrtf((float)cnt[s3] + 1.0f)*dn : 0.f;
      __half2 wh0 = __half2half2(__float2half(w0));
      __half2 wh1 = __half2half2(__float2half(w1));
      __half2 wh2 = __half2half2(__float2half(w2));
      __half2 wh3 = __half2half2(__float2half(w3));
      const ushort* r0 = xTh + (size_t)s0*384;
      const ushort* r1 = xTh + (size_t)s1*384;
      const ushort* r2 = xTh + (size_t)s2*384;
      const ushort* r3 = xTh + (size_t)s3*384;
      uint4 A0 = *(const uint4*)(r0 + lh*8);
      uint4 A1 = *(const uint4*)(r1 + lh*8);
      uint4 A2 = *(const uint4*)(r2 + lh*8);
      uint4 A3 = *(const uint4*)(r3 + lh*8);
      uint2 B0 = *(const uint2*)(r0 + 256 + lh*4);
      uint2 B1 = *(const uint2*)(r1 + 256 + lh*4);
      uint2 B2 = *(const uint2*)(r2 + 256 + lh*4);
      uint2 B3 = *(const uint2*)(r3 + 256 + lh*4);
      acch8(hA, A0, wh0); acch4(hB2, B0, wh0);
      acch8(hA, A1, wh1); acch4(hB2, B1, wh1);
      acch8(hA, A2, wh2); acch4(hB2, B2, wh2);
      acch8(hA, A3, wh3); acch4(hB2, B3, wh3);
    }
    // reduce across the two halves (packed)
    #pragma unroll
    for(int k=0;k<4;k++){
      uint v = __shfl_xor(*(uint*)&hA[k], 32, 64);
      hA[k] = __hadd2(hA[k], *(__half2*)&v);
    }
    #pragma unroll
    for(int k=0;k<2;k++){
      uint v = __shfl_xor(*(uint*)&hB2[k], 32, 64);
      hB2[k] = __hadd2(hB2[k], *(__half2*)&v);
    }

    if(half == 0){
      __half2 snh = __half2half2(__float2half(dn*dn));
      const ushort* rS = xTh + (size_t)n*384;
      uint4 AS = *(const uint4*)(rS + lh*8);
      uint2 BS = *(const uint2*)(rS + 256 + lh*4);
      acch8(hA, AS, snh); acch4(hB2, BS, snh);
      ushort* row = &agg_lds[nl][0];
      uint4 h0;
      h0.x = *(uint*)&hA[0];
      h0.y = *(uint*)&hA[1];
      h0.z = *(uint*)&hA[2];
      h0.w = *(uint*)&hA[3];
      *(uint4*)(row + lh*8) = h0;
      uint2 hBo;
      hBo.x = *(uint*)&hB2[0];
      hBo.y = *(uint*)&hB2[1];
      *(uint2*)(row + 256 + lh*4) = hBo;
    }
  }
  __syncthreads();

  // ---- Phase B: GRU ----
  const int nd = l & 15, g = l >> 4;
  const int chB = 16*w;
  const f16x8 zf = (f16x8){0,0,0,0,0,0,0,0};
  f16x8 ar0,ar1,az0,az1,an0,an1, mr,mz,mn;
  {
    const int rr =        chB + nd;
    const int rz =  HH  + chB + nd;
    const int rn = 2*HH + chB + nd;
    ar0 = *(const f16x8*)(whhF + rr*HH      + g*8);
    ar1 = *(const f16x8*)(whhF + rr*HH + 32 + g*8);
    az0 = *(const f16x8*)(whhF + rz*HH      + g*8);
    az1 = *(const f16x8*)(whhF + rz*HH + 32 + g*8);
    an0 = *(const f16x8*)(whhF + rn*HH      + g*8);
    an1 = *(const f16x8*)(whhF + rn*HH + 32 + g*8);
    mr = zf; mz = zf; mn = zf;
    if(g < 2){
      mr = *(const f16x8*)(m1F + rr*FF + g*8);
      mz = *(const f16x8*)(m1F + rz*FF + g*8);
      mn = *(const f16x8*)(m1F + rn*FF + g*8);
    } else if(g == 2){
      mr[0] = (_Float16)(c1[rr] + bhh[rr]);
      mz[0] = (_Float16)(c1[rz] + bhh[rz]);
      mn[0] = (_Float16)(c1[rn]);
    }
  }
  float4 bb = *(const float4*)(bhh + 2*HH + chB + g*4);

  float hreg[4] = {0.f,0.f,0.f,0.f};
  f16x8 cB = zf;            // bias/zero frag for g>=2
  if(g==2) cB[0] = (_Float16)1.0f;

  const int swz = (nd & 7) << 2;

  for(int t=0; t<TT; t++){
    const uint* cb = hb[t & 1];
    uint* nb = hb[(t & 1) ^ 1];

    f16x8 hB0 = *(const f16x8*)(cb + nd*32 + ((g*4)      ^ swz));
    f16x8 hB1 = *(const f16x8*)(cb + nd*32 + ((16 + g*4) ^ swz));
    f16x8 cAg = cB;
    if(g < 2) cAg = *(const f16x8*)&agg_lds[nd][t*16 + g*8];

    f32x4 R  = {0.f,0.f,0.f,0.f};
    f32x4 Z  = {0.f,0.f,0.f,0.f};
    f32x4 Nh = {0.f,0.f,0.f,0.f};
    f32x4 Ni = {0.f,0.f,0.f,0.f};
    R  = __builtin_amdgcn_mfma_f32_16x16x32_f16(ar0, hB0, R , 0,0,0);
    R  = __builtin_amdgcn_mfma_f32_16x16x32_f16(ar1, hB1, R , 0,0,0);
    R  = __builtin_amdgcn_mfma_f32_16x16x32_f16(mr,  cAg, R , 0,0,0);
    Z  = __builtin_amdgcn_mfma_f32_16x16x32_f16(az0, hB0, Z , 0,0,0);
    Z  = __builtin_amdgcn_mfma_f32_16x16x32_f16(az1, hB1, Z , 0,0,0);
    Z  = __builtin_amdgcn_mfma_f32_16x16x32_f16(mz,  cAg, Z , 0,0,0);
    Nh = __builtin_amdgcn_mfma_f32_16x16x32_f16(an0, hB0, Nh, 0,0,0);
    Nh = __builtin_amdgcn_mfma_f32_16x16x32_f16(an1, hB1, Nh, 0,0,0);
    Ni = __builtin_amdgcn_mfma_f32_16x16x32_f16(mn,  cAg, Ni, 0,0,0);

    const float bbv[4] = {bb.x, bb.y, bb.z, bb.w};
    #pragma unroll
    for(int i=0;i<4;i++){
      float r_ = sigmoid_f(R[i]);
      float z_ = sigmoid_f(Z[i]);
      float nn = tanh_f(Ni[i] + r_*(Nh[i] + bbv[i]));
      hreg[i] = nn + z_*(hreg[i] - nn);
    }
    uint2 pk;
    pk.x = pack_h2(hreg[0], hreg[1]);
    pk.y = pack_h2(hreg[2], hreg[3]);
    *(uint2*)(nb + nd*32 + ((8*w + 2*g) ^ swz)) = pk;

    __syncthreads();
  }

  // ---- Phase C: fused linear head ----
  float* hs = (float*)hb;
  #pragma unroll
  for(int i=0;i<4;i++) hs[nd*64 + chB + g*4 + i] = hreg[i];
  __syncthreads();
  if(tid < 16*P){
    int ndl = tid & 15, p = tid >> 4;
    int node2 = nbase + ndl;
    if(node2 < N){
      float acc = lin_b[p];
      const float* hrow = hs + ndl*64;
      #pragma unroll
      for(int q=0;q<16;q++){
        float4 v = *(const float4*)(hrow + q*4);
        float4 lw = *(const float4*)(lin_w + p*HH + q*4);
        acc += v.x*lw.x + v.y*lw.y + v.z*lw.z + v.w*lw.w;
      }
      out[(size_t)p*N + node2] = acc;
    }
  }
}

extern "C" void kernel_launch(void* const* d_in, const int* in_sizes, int n_in,
                              void* d_out, int out_size, void* d_ws, size_t ws_size,
                              hipStream_t stream){
  const float* x     = (const float*)d_in[0];
  const float* gcn_w = (const float*)d_in[2];
  const float* gcn_b = (const float*)d_in[3];
  const float* w_ih  = (const float*)d_in[4];
  const float* w_hh  = (const float*)d_in[5];
  const float* b_ih  = (const float*)d_in[6];
  const float* b_hh  = (const float*)d_in[7];
  const float* lin_w = (const float*)d_in[8];
  const float* lin_b = (const float*)d_in[9];
  const int*   ei    = (const int*)d_in[10];
  const int E = in_sizes[10]/2;
  const int N = in_sizes[0]/(TT*FF);
  const int P = in_sizes[9];

  char* wsp = (char*)d_ws;
  auto alloc = [&](size_t bytes)->void*{ void* p = wsp; wsp += (bytes + 255) & ~(size_t)255; return p; };
  int*    cnt      = (int*)   alloc((size_t)N*4);
  ushort* ell      = (ushort*)alloc((size_t)N*ELLW*2);
  ushort* xTh      = (ushort*)alloc((size_t)N*384*2);
  ushort* m1F      = (ushort*)alloc((size_t)GG*FF*2);
  float*  c1       = (float*) alloc((size_t)GG*4);
  ushort* whhF     = (ushort*)alloc((size_t)GG*HH*2);

  hipMemsetAsync(cnt, 0, (size_t)N*4, stream);

  const int GX = (N + 15)/16;
  const int GD = (E + 255)/256;
  const int GP = (GG*HH + 255)/256;
  k_pre2 <<<GX + GD + GP, 256, 0, stream>>>(x, xTh, ei, E, cnt, ell,
                                            gcn_w, gcn_b, w_ih, b_ih, w_hh,
                                            m1F, c1, whhF, N, GX, GD);
  k_fused<<<(N+15)/16, 256, 0, stream>>>(xTh, cnt, ell, whhF, m1F, c1, b_hh,
                                         lin_w, lin_b, (float*)d_out, N, P);
}

// Round 23
// 340.816 us; speedup vs baseline: 1.7282x; 1.0148x over previous
//
#include <hip/hip_runtime.h>
#include <hip/hip_bf16.h>
#include <hip/hip_fp16.h>

#define TT 24
#define FF 16
#define HH 64
#define GG 192   // 3*HH
#define ELLW 96  // ELL stride; Poisson(32) max deg ~66 << 96
#define AROW 396 // agg_lds row stride

typedef __attribute__((ext_vector_type(4))) float f32x4;
typedef __attribute__((ext_vector_type(8))) _Float16 f16x8;

__device__ __forceinline__ float fast_rcp(float x){ return __builtin_amdgcn_rcpf(x); }
__device__ __forceinline__ float sigmoid_f(float x){
  return fast_rcp(1.0f + __expf(-x));
}
__device__ __forceinline__ float tanh_f(float x){
  float e = __expf(-2.0f * fabsf(x));
  float th = (1.0f - e) * fast_rcp(1.0f + e);
  return copysignf(th, x);
}
__device__ __forceinline__ uint pack_h2(float a, float b){
  ushort ha = __half_as_ushort(__float2half(a));
  ushort hb = __half_as_ushort(__float2half(b));
  return (uint)ha | ((uint)hb << 16);
}
__device__ __forceinline__ void acch8(__half2* a, uint4 u, __half2 wh){
  a[0] = __hfma2(*(__half2*)&u.x, wh, a[0]);
  a[1] = __hfma2(*(__half2*)&u.y, wh, a[1]);
  a[2] = __hfma2(*(__half2*)&u.z, wh, a[2]);
  a[3] = __hfma2(*(__half2*)&u.w, wh, a[3]);
}
__device__ __forceinline__ void acch4(__half2* a, uint2 u, __half2 wh){
  a[0] = __hfma2(*(__half2*)&u.x, wh, a[0]);
  a[1] = __hfma2(*(__half2*)&u.y, wh, a[1]);
}

// ---------------- fused prologue: xt2 || ELL-fill (ushort) || prep ----------------
__global__ __launch_bounds__(256)
void k_pre2(const float* __restrict__ x, ushort* __restrict__ xTh,
            const int* __restrict__ ei, int E, int* __restrict__ cnt, ushort* __restrict__ ell,
            const float* __restrict__ gcn_w, const float* __restrict__ gcn_b,
            const float* __restrict__ w_ih, const float* __restrict__ b_ih,
            const float* __restrict__ w_hh,
            ushort* __restrict__ m1F, float* __restrict__ c1, ushort* __restrict__ whhF,
            int N, int GX, int GD){
  __shared__ ushort tile[16][392];
  const int bid = blockIdx.x;
  const int tid = threadIdx.x;
  if(bid < GX){
    const int nbase = bid * 16;
    const int nd = tid >> 4, f = tid & 15;
    const int n = nbase + nd;
    for(int t=0; t<TT; t++){
      float v = (n < N) ? x[((size_t)t*N + n)*FF + f] : 0.f;
      tile[nd][t*16 + f] = __half_as_ushort(__float2half(v));
    }
    __syncthreads();
    uint* xo = (uint*)xTh;
    for(int i = tid; i < 16*192; i += 256){
      int d = i / 192, pos = i - d*192;
      int nn = nbase + d;
      if(nn < N) xo[(size_t)nn*192 + pos] = *(uint*)&tile[d][pos*2];
    }
  } else if(bid < GX + GD){
    // single-pass ELL build: cnt doubles as degree
    int i = (bid - GX)*256 + tid;
    if(i < E){
      int s = ei[i], d = ei[E+i];
      int slot = atomicAdd(&cnt[d], 1);
      if(slot < ELLW) ell[(size_t)d*ELLW + slot] = (ushort)s;
    }
  } else {
    int t2 = (bid - GX - GD)*256 + tid;
    if(t2 < GG*FF){
      int j = t2 >> 4, f = t2 & 15;
      float s = 0.f;
      for(int k=0;k<HH;k++) s += gcn_w[f*HH+k]*w_ih[j*HH+k];
      m1F[t2] = __half_as_ushort(__float2half(s));
    } else if (t2 < GG*FF + GG){
      int j = t2 - GG*FF;
      float s = b_ih[j];
      for(int k=0;k<HH;k++) s += gcn_b[k]*w_ih[j*HH+k];
      c1[j] = s;
    }
    if(t2 < GG*HH){
      whhF[t2] = __half_as_ushort(__float2half(w_hh[t2]));
    }
  }
}

// ---------------- dinvh table (half), after cnt is final ----------------
__global__ void k_dinvh(const int* __restrict__ cnt, ushort* __restrict__ dinvh, int N){
  int i = blockIdx.x*blockDim.x + threadIdx.x;
  if(i<N) dinvh[i] = __half_as_ushort(__float2half(rsqrtf((float)cnt[i] + 1.0f)));
}

// ---------------- fused agg + GRU + head: block = 16 nodes, 4 waves ----------------
__global__ __launch_bounds__(256, 4)
void k_fused(const ushort* __restrict__ xTh, const int* __restrict__ cnt,
             const ushort* __restrict__ ell, const ushort* __restrict__ dinvh,
             const ushort* __restrict__ whhF, const ushort* __restrict__ m1F,
             const float* __restrict__ c1, const float* __restrict__ bhh,
             const float* __restrict__ lin_w, const float* __restrict__ lin_b,
             float* __restrict__ out, int N, int P){
  __shared__ __align__(16) ushort agg_lds[16][AROW];  // pos = t*16+f
  __shared__ __align__(16) uint hb[2][512];           // 4 KB h dbuf (f16)
  __shared__ __align__(16) uint ell_w[4][48];         // per-wave staged ELL row
  const int tid = threadIdx.x;
  const int l = tid & 63, w = tid >> 6;
  const int half = l >> 5, lh = l & 31;
  const int nbase = blockIdx.x * 16;

  // zero h buffer 0 (covered by the phase-A barrier)
  for(int i=tid; i<512; i+=256) hb[0][i]=0u;

  // ---- Phase A: aggregation, 4 nodes per wave; f16 packed accumulation ----
  const ushort* myell = (const ushort*)ell_w[w];
  for(int q=0; q<4; q++){
    const int nl = w*4 + q;
    const int n = min(nbase + nl, N-1);
    __half2 hA[4], hB2[2];
    hA[0]=__half2{0,0}; hA[1]=__half2{0,0}; hA[2]=__half2{0,0}; hA[3]=__half2{0,0};
    hB2[0]=__half2{0,0}; hB2[1]=__half2{0,0};
    const __half dnh = __ushort_as_half(dinvh[n]);
    const int hi = min(cnt[n], ELLW);

    // stage the 96-entry ELL row (48 dwords) into wave-private LDS, coalesced
    if(l < 48) ell_w[w][l] = *(const uint*)(ell + (uint)n*ELLW + l*2);

    for(int j = 0; j < hi; j += 8){
      int j0 = j     + half;
      int j1 = j + 2 + half;
      int j2 = j + 4 + half;
      int j3 = j + 6 + half;
      bool k0 = j0 < hi, k1 = j1 < hi, k2 = j2 < hi, k3 = j3 < hi;
      int s0 = n, s1 = n, s2 = n, s3 = n;
      if(k0) s0 = myell[j0];
      if(k1) s1 = myell[j1];
      if(k2) s2 = myell[j2];
      if(k3) s3 = myell[j3];
      __half z0 = __ushort_as_half((ushort)0);
      __half w0 = k0 ? __hmul(__ushort_as_half(dinvh[s0]), dnh) : z0;
      __half w1 = k1 ? __hmul(__ushort_as_half(dinvh[s1]), dnh) : z0;
      __half w2 = k2 ? __hmul(__ushort_as_half(dinvh[s2]), dnh) : z0;
      __half w3 = k3 ? __hmul(__ushort_as_half(dinvh[s3]), dnh) : z0;
      __half2 wh0 = __half2half2(w0);
      __half2 wh1 = __half2half2(w1);
      __half2 wh2 = __half2half2(w2);
      __half2 wh3 = __half2half2(w3);
      const ushort* r0 = xTh + (uint)s0*384u;
      const ushort* r1 = xTh + (uint)s1*384u;
      const ushort* r2 = xTh + (uint)s2*384u;
      const ushort* r3 = xTh + (uint)s3*384u;
      uint4 A0 = *(const uint4*)(r0 + lh*8);
      uint4 A1 = *(const uint4*)(r1 + lh*8);
      uint4 A2 = *(const uint4*)(r2 + lh*8);
      uint4 A3 = *(const uint4*)(r3 + lh*8);
      uint2 B0 = *(const uint2*)(r0 + 256 + lh*4);
      uint2 B1 = *(const uint2*)(r1 + 256 + lh*4);
      uint2 B2 = *(const uint2*)(r2 + 256 + lh*4);
      uint2 B3 = *(const uint2*)(r3 + 256 + lh*4);
      acch8(hA, A0, wh0); acch4(hB2, B0, wh0);
      acch8(hA, A1, wh1); acch4(hB2, B1, wh1);
      acch8(hA, A2, wh2); acch4(hB2, B2, wh2);
      acch8(hA, A3, wh3); acch4(hB2, B3, wh3);
    }
    // reduce across the two halves (packed)
    #pragma unroll
    for(int k=0;k<4;k++){
      uint v = __shfl_xor(*(uint*)&hA[k], 32, 64);
      hA[k] = __hadd2(hA[k], *(__half2*)&v);
    }
    #pragma unroll
    for(int k=0;k<2;k++){
      uint v = __shfl_xor(*(uint*)&hB2[k], 32, 64);
      hB2[k] = __hadd2(hB2[k], *(__half2*)&v);
    }

    if(half == 0){
      __half2 snh = __half2half2(__hmul(dnh, dnh));
      const ushort* rS = xTh + (uint)n*384u;
      uint4 AS = *(const uint4*)(rS + lh*8);
      uint2 BS = *(const uint2*)(rS + 256 + lh*4);
      acch8(hA, AS, snh); acch4(hB2, BS, snh);
      ushort* row = &agg_lds[nl][0];
      uint4 h0;
      h0.x = *(uint*)&hA[0];
      h0.y = *(uint*)&hA[1];
      h0.z = *(uint*)&hA[2];
      h0.w = *(uint*)&hA[3];
      *(uint4*)(row + lh*8) = h0;
      uint2 hBo;
      hBo.x = *(uint*)&hB2[0];
      hBo.y = *(uint*)&hB2[1];
      *(uint2*)(row + 256 + lh*4) = hBo;
    }
  }
  __syncthreads();

  // ---- Phase B: GRU ----
  const int nd = l & 15, g = l >> 4;
  const int chB = 16*w;
  const f16x8 zf = (f16x8){0,0,0,0,0,0,0,0};
  f16x8 ar0,ar1,az0,az1,an0,an1, mr,mz,mn;
  {
    const int rr =        chB + nd;
    const int rz =  HH  + chB + nd;
    const int rn = 2*HH + chB + nd;
    ar0 = *(const f16x8*)(whhF + rr*HH      + g*8);
    ar1 = *(const f16x8*)(whhF + rr*HH + 32 + g*8);
    az0 = *(const f16x8*)(whhF + rz*HH      + g*8);
    az1 = *(const f16x8*)(whhF + rz*HH + 32 + g*8);
    an0 = *(const f16x8*)(whhF + rn*HH      + g*8);
    an1 = *(const f16x8*)(whhF + rn*HH + 32 + g*8);
    mr = zf; mz = zf; mn = zf;
    if(g < 2){
      mr = *(const f16x8*)(m1F + rr*FF + g*8);
      mz = *(const f16x8*)(m1F + rz*FF + g*8);
      mn = *(const f16x8*)(m1F + rn*FF + g*8);
    } else if(g == 2){
      mr[0] = (_Float16)(c1[rr] + bhh[rr]);
      mz[0] = (_Float16)(c1[rz] + bhh[rz]);
      mn[0] = (_Float16)(c1[rn]);
    }
  }
  float4 bb = *(const float4*)(bhh + 2*HH + chB + g*4);

  float hreg[4] = {0.f,0.f,0.f,0.f};
  f16x8 cB = zf;            // bias/zero frag for g>=2
  if(g==2) cB[0] = (_Float16)1.0f;

  const int swz = (nd & 7) << 2;

  for(int t=0; t<TT; t++){
    const uint* cb = hb[t & 1];
    uint* nb = hb[(t & 1) ^ 1];

    f16x8 hB0 = *(const f16x8*)(cb + nd*32 + ((g*4)      ^ swz));
    f16x8 hB1 = *(const f16x8*)(cb + nd*32 + ((16 + g*4) ^ swz));
    f16x8 cAg = cB;
    if(g < 2) cAg = *(const f16x8*)&agg_lds[nd][t*16 + g*8];

    f32x4 R  = {0.f,0.f,0.f,0.f};
    f32x4 Z  = {0.f,0.f,0.f,0.f};
    f32x4 Nh = {0.f,0.f,0.f,0.f};
    f32x4 Ni = {0.f,0.f,0.f,0.f};
    R  = __builtin_amdgcn_mfma_f32_16x16x32_f16(ar0, hB0, R , 0,0,0);
    R  = __builtin_amdgcn_mfma_f32_16x16x32_f16(ar1, hB1, R , 0,0,0);
    R  = __builtin_amdgcn_mfma_f32_16x16x32_f16(mr,  cAg, R , 0,0,0);
    Z  = __builtin_amdgcn_mfma_f32_16x16x32_f16(az0, hB0, Z , 0,0,0);
    Z  = __builtin_amdgcn_mfma_f32_16x16x32_f16(az1, hB1, Z , 0,0,0);
    Z  = __builtin_amdgcn_mfma_f32_16x16x32_f16(mz,  cAg, Z , 0,0,0);
    Nh = __builtin_amdgcn_mfma_f32_16x16x32_f16(an0, hB0, Nh, 0,0,0);
    Nh = __builtin_amdgcn_mfma_f32_16x16x32_f16(an1, hB1, Nh, 0,0,0);
    Ni = __builtin_amdgcn_mfma_f32_16x16x32_f16(mn,  cAg, Ni, 0,0,0);

    const float bbv[4] = {bb.x, bb.y, bb.z, bb.w};
    #pragma unroll
    for(int i=0;i<4;i++){
      float r_ = sigmoid_f(R[i]);
      float z_ = sigmoid_f(Z[i]);
      float nn = tanh_f(Ni[i] + r_*(Nh[i] + bbv[i]));
      hreg[i] = nn + z_*(hreg[i] - nn);
    }
    if(t+1 < TT){
      uint2 pk;
      pk.x = pack_h2(hreg[0], hreg[1]);
      pk.y = pack_h2(hreg[2], hreg[3]);
      *(uint2*)(nb + nd*32 + ((8*w + 2*g) ^ swz)) = pk;
      __syncthreads();
    }
  }

  // ---- Phase C: fused linear head ----
  __syncthreads();   // all waves done with hb reads
  float* hs = (float*)hb;
  #pragma unroll
  for(int i=0;i<4;i++) hs[nd*64 + chB + g*4 + i] = hreg[i];
  __syncthreads();
  if(tid < 16*P){
    int ndl = tid & 15, p = tid >> 4;
    int node2 = nbase + ndl;
    if(node2 < N){
      float acc = lin_b[p];
      const float* hrow = hs + ndl*64;
      #pragma unroll
      for(int q=0;q<16;q++){
        float4 v = *(const float4*)(hrow + q*4);
        float4 lw = *(const float4*)(lin_w + p*HH + q*4);
        acc += v.x*lw.x + v.y*lw.y + v.z*lw.z + v.w*lw.w;
      }
      out[(size_t)p*N + node2] = acc;
    }
  }
}

extern "C" void kernel_launch(void* const* d_in, const int* in_sizes, int n_in,
                              void* d_out, int out_size, void* d_ws, size_t ws_size,
                              hipStream_t stream){
  const float* x     = (const float*)d_in[0];
  const float* gcn_w = (const float*)d_in[2];
  const float* gcn_b = (const float*)d_in[3];
  const float* w_ih  = (const float*)d_in[4];
  const float* w_hh  = (const float*)d_in[5];
  const float* b_ih  = (const float*)d_in[6];
  const float* b_hh  = (const float*)d_in[7];
  const float* lin_w = (const float*)d_in[8];
  const float* lin_b = (const float*)d_in[9];
  const int*   ei    = (const int*)d_in[10];
  const int E = in_sizes[10]/2;
  const int N = in_sizes[0]/(TT*FF);
  const int P = in_sizes[9];

  char* wsp = (char*)d_ws;
  auto alloc = [&](size_t bytes)->void*{ void* p = wsp; wsp += (bytes + 255) & ~(size_t)255; return p; };
  int*    cnt      = (int*)   alloc((size_t)N*4);
  ushort* dinvh    = (ushort*)alloc((size_t)N*2);
  ushort* ell      = (ushort*)alloc((size_t)N*ELLW*2);
  ushort* xTh      = (ushort*)alloc((size_t)N*384*2);
  ushort* m1F      = (ushort*)alloc((size_t)GG*FF*2);
  float*  c1       = (float*) alloc((size_t)GG*4);
  ushort* whhF     = (ushort*)alloc((size_t)GG*HH*2);

  hipMemsetAsync(cnt, 0, (size_t)N*4, stream);

  const int GX = (N + 15)/16;
  const int GD = (E + 255)/256;
  const int GP = (GG*HH + 255)/256;
  k_pre2 <<<GX + GD + GP, 256, 0, stream>>>(x, xTh, ei, E, cnt, ell,
                                            gcn_w, gcn_b, w_ih, b_ih, w_hh,
                                            m1F, c1, whhF, N, GX, GD);
  k_dinvh<<<(N+255)/256, 256, 0, stream>>>(cnt, dinvh, N);
  k_fused<<<(N+15)/16, 256, 0, stream>>>(xTh, cnt, ell, dinvh, whhF, m1F, c1, b_hh,
                                         lin_w, lin_b, (float*)d_out, N, P);
}

// Round 24
// 324.722 us; speedup vs baseline: 1.8138x; 1.0496x over previous
//
#include <hip/hip_runtime.h>
#include <hip/hip_bf16.h>
#include <hip/hip_fp16.h>

#define TT 24
#define FF 16
#define HH 64
#define GG 192   // 3*HH
#define ELLW 96  // ELL stride; Poisson(32) max deg ~66 << 96
#define AROW 396 // agg_lds row stride

typedef __attribute__((ext_vector_type(4))) float f32x4;
typedef __attribute__((ext_vector_type(8))) _Float16 f16x8;

__device__ __forceinline__ float fast_rcp(float x){ return __builtin_amdgcn_rcpf(x); }
__device__ __forceinline__ float sigmoid_f(float x){
  return fast_rcp(1.0f + __expf(-x));
}
__device__ __forceinline__ float tanh_f(float x){
  float e = __expf(-2.0f * fabsf(x));
  float th = (1.0f - e) * fast_rcp(1.0f + e);
  return copysignf(th, x);
}
__device__ __forceinline__ uint pack_h2(float a, float b){
  ushort ha = __half_as_ushort(__float2half(a));
  ushort hb = __half_as_ushort(__float2half(b));
  return (uint)ha | ((uint)hb << 16);
}
__device__ __forceinline__ void adda8(__half2* a, uint4 u){
  a[0] = __hadd2(a[0], *(__half2*)&u.x);
  a[1] = __hadd2(a[1], *(__half2*)&u.y);
  a[2] = __hadd2(a[2], *(__half2*)&u.z);
  a[3] = __hadd2(a[3], *(__half2*)&u.w);
}
__device__ __forceinline__ void adda4(__half2* a, uint2 u){
  a[0] = __hadd2(a[0], *(__half2*)&u.x);
  a[1] = __hadd2(a[1], *(__half2*)&u.y);
}

// ---------------- fused prologue: xt2 || ELL-fill (ushort) || prep ----------------
__global__ __launch_bounds__(256)
void k_pre2(const float* __restrict__ x, ushort* __restrict__ xTh,
            const int* __restrict__ ei, int E, int* __restrict__ cnt, ushort* __restrict__ ell,
            const float* __restrict__ gcn_w, const float* __restrict__ gcn_b,
            const float* __restrict__ w_ih, const float* __restrict__ b_ih,
            const float* __restrict__ w_hh,
            ushort* __restrict__ m1F, float* __restrict__ c1, ushort* __restrict__ whhF,
            int N, int GX, int GD){
  __shared__ ushort tile[16][392];
  const int bid = blockIdx.x;
  const int tid = threadIdx.x;
  if(bid < GX){
    const int nbase = bid * 16;
    const int nd = tid >> 4, f = tid & 15;
    const int n = nbase + nd;
    for(int t=0; t<TT; t++){
      float v = (n < N) ? x[((size_t)t*N + n)*FF + f] : 0.f;
      tile[nd][t*16 + f] = __half_as_ushort(__float2half(v));
    }
    __syncthreads();
    uint* xo = (uint*)xTh;
    for(int i = tid; i < 16*192; i += 256){
      int d = i / 192, pos = i - d*192;
      int nn = nbase + d;
      if(nn < N) xo[(size_t)nn*192 + pos] = *(uint*)&tile[d][pos*2];
    }
  } else if(bid < GX + GD){
    // single-pass ELL build: cnt doubles as degree
    int i = (bid - GX)*256 + tid;
    if(i < E){
      int s = ei[i], d = ei[E+i];
      int slot = atomicAdd(&cnt[d], 1);
      if(slot < ELLW) ell[(size_t)d*ELLW + slot] = (ushort)s;
    }
  } else {
    int t2 = (bid - GX - GD)*256 + tid;
    if(t2 < GG*FF){
      int j = t2 >> 4, f = t2 & 15;
      float s = 0.f;
      for(int k=0;k<HH;k++) s += gcn_w[f*HH+k]*w_ih[j*HH+k];
      m1F[t2] = __half_as_ushort(__float2half(s));
    } else if (t2 < GG*FF + GG){
      int j = t2 - GG*FF;
      float s = b_ih[j];
      for(int k=0;k<HH;k++) s += gcn_b[k]*w_ih[j*HH+k];
      c1[j] = s;
    }
    if(t2 < GG*HH){
      whhF[t2] = __half_as_ushort(__float2half(w_hh[t2]));
    }
  }
}

// ---------------- scale pass: xTh[n] *= dinv[n], zero row N, emit dinvh ----------------
__global__ void k_scale(const int* __restrict__ cnt, ushort* __restrict__ xTh,
                        ushort* __restrict__ dinvh, int N){
  int i = blockIdx.x*blockDim.x + threadIdx.x;
  int total = (N+1)*192;
  if(i >= total) return;
  int n = i / 192, d = i - n*192;
  uint* p = (uint*)xTh;
  if(n >= N){ p[i] = 0u; return; }   // zero row N (inactive-lane target)
  float dv = rsqrtf((float)cnt[n] + 1.0f);
  __half2 dh2 = __half2half2(__float2half(dv));
  uint v = p[i];
  __half2 hv = *(__half2*)&v;
  hv = __hmul2(hv, dh2);
  p[i] = *(uint*)&hv;
  if(d == 0) dinvh[n] = __half_as_ushort(__float2half(dv));
}

// ---------------- fused agg + GRU + head: block = 16 nodes, 4 waves ----------------
__global__ __launch_bounds__(256, 4)
void k_fused(const ushort* __restrict__ xTh, const int* __restrict__ cnt,
             const ushort* __restrict__ ell, const ushort* __restrict__ dinvh,
             const ushort* __restrict__ whhF, const ushort* __restrict__ m1F,
             const float* __restrict__ c1, const float* __restrict__ bhh,
             const float* __restrict__ lin_w, const float* __restrict__ lin_b,
             float* __restrict__ out, int N, int P){
  __shared__ __align__(16) ushort agg_lds[16][AROW];  // pos = t*16+f
  __shared__ __align__(16) uint hb[2][512];           // 4 KB h dbuf (f16)
  __shared__ __align__(16) uint ell_w[4][48];         // per-wave staged ELL row
  const int tid = threadIdx.x;
  const int l = tid & 63, w = tid >> 6;
  const int half = l >> 5, lh = l & 31;
  const int nbase = blockIdx.x * 16;

  // zero h buffer 0 (covered by the phase-A barrier)
  for(int i=tid; i<512; i+=256) hb[0][i]=0u;

  // ---- Phase A: unweighted accumulation of pre-scaled rows ----
  const ushort* myell = (const ushort*)ell_w[w];
  for(int q=0; q<4; q++){
    const int nl = w*4 + q;
    const int n = min(nbase + nl, N-1);
    __half2 hA[4], hB2[2];
    hA[0]=__half2{0,0}; hA[1]=__half2{0,0}; hA[2]=__half2{0,0}; hA[3]=__half2{0,0};
    hB2[0]=__half2{0,0}; hB2[1]=__half2{0,0};
    const __half dnh = __ushort_as_half(dinvh[n]);
    const int hi = min(cnt[n], ELLW);

    // stage the 96-entry ELL row (48 dwords) into wave-private LDS, coalesced
    if(l < 48) ell_w[w][l] = *(const uint*)(ell + (uint)n*ELLW + l*2);

    for(int j = 0; j < hi; j += 8){
      int j0 = j     + half;
      int j1 = j + 2 + half;
      int j2 = j + 4 + half;
      int j3 = j + 6 + half;
      bool k0 = j0 < hi, k1 = j1 < hi, k2 = j2 < hi, k3 = j3 < hi;
      int s0 = N, s1 = N, s2 = N, s3 = N;     // row N is all zeros
      if(k0) s0 = myell[j0];
      if(k1) s1 = myell[j1];
      if(k2) s2 = myell[j2];
      if(k3) s3 = myell[j3];
      const ushort* r0 = xTh + (uint)s0*384u;
      const ushort* r1 = xTh + (uint)s1*384u;
      const ushort* r2 = xTh + (uint)s2*384u;
      const ushort* r3 = xTh + (uint)s3*384u;
      uint4 A0 = *(const uint4*)(r0 + lh*8);
      uint4 A1 = *(const uint4*)(r1 + lh*8);
      uint4 A2 = *(const uint4*)(r2 + lh*8);
      uint4 A3 = *(const uint4*)(r3 + lh*8);
      uint2 B0 = *(const uint2*)(r0 + 256 + lh*4);
      uint2 B1 = *(const uint2*)(r1 + 256 + lh*4);
      uint2 B2 = *(const uint2*)(r2 + 256 + lh*4);
      uint2 B3 = *(const uint2*)(r3 + 256 + lh*4);
      adda8(hA, A0); adda4(hB2, B0);
      adda8(hA, A1); adda4(hB2, B1);
      adda8(hA, A2); adda4(hB2, B2);
      adda8(hA, A3); adda4(hB2, B3);
    }
    // reduce across the two halves (packed)
    #pragma unroll
    for(int k=0;k<4;k++){
      uint v = __shfl_xor(*(uint*)&hA[k], 32, 64);
      hA[k] = __hadd2(hA[k], *(__half2*)&v);
    }
    #pragma unroll
    for(int k=0;k<2;k++){
      uint v = __shfl_xor(*(uint*)&hB2[k], 32, 64);
      hB2[k] = __hadd2(hB2[k], *(__half2*)&v);
    }

    if(half == 0){
      // add self pre-scaled row, then single final scale by dinv[n]
      const ushort* rS = xTh + (uint)n*384u;
      uint4 AS = *(const uint4*)(rS + lh*8);
      uint2 BS = *(const uint2*)(rS + 256 + lh*4);
      adda8(hA, AS); adda4(hB2, BS);
      __half2 dnh2 = __half2half2(dnh);
      #pragma unroll
      for(int k=0;k<4;k++) hA[k] = __hmul2(hA[k], dnh2);
      #pragma unroll
      for(int k=0;k<2;k++) hB2[k] = __hmul2(hB2[k], dnh2);
      ushort* row = &agg_lds[nl][0];
      uint4 h0;
      h0.x = *(uint*)&hA[0];
      h0.y = *(uint*)&hA[1];
      h0.z = *(uint*)&hA[2];
      h0.w = *(uint*)&hA[3];
      *(uint4*)(row + lh*8) = h0;
      uint2 hBo;
      hBo.x = *(uint*)&hB2[0];
      hBo.y = *(uint*)&hB2[1];
      *(uint2*)(row + 256 + lh*4) = hBo;
    }
  }
  __syncthreads();

  // ---- Phase B: GRU ----
  const int nd = l & 15, g = l >> 4;
  const int chB = 16*w;
  const f16x8 zf = (f16x8){0,0,0,0,0,0,0,0};
  f16x8 ar0,ar1,az0,az1,an0,an1, mr,mz,mn;
  {
    const int rr =        chB + nd;
    const int rz =  HH  + chB + nd;
    const int rn = 2*HH + chB + nd;
    ar0 = *(const f16x8*)(whhF + rr*HH      + g*8);
    ar1 = *(const f16x8*)(whhF + rr*HH + 32 + g*8);
    az0 = *(const f16x8*)(whhF + rz*HH      + g*8);
    az1 = *(const f16x8*)(whhF + rz*HH + 32 + g*8);
    an0 = *(const f16x8*)(whhF + rn*HH      + g*8);
    an1 = *(const f16x8*)(whhF + rn*HH + 32 + g*8);
    mr = zf; mz = zf; mn = zf;
    if(g < 2){
      mr = *(const f16x8*)(m1F + rr*FF + g*8);
      mz = *(const f16x8*)(m1F + rz*FF + g*8);
      mn = *(const f16x8*)(m1F + rn*FF + g*8);
    } else if(g == 2){
      mr[0] = (_Float16)(c1[rr] + bhh[rr]);
      mz[0] = (_Float16)(c1[rz] + bhh[rz]);
      mn[0] = (_Float16)(c1[rn]);
    }
  }
  float4 bb = *(const float4*)(bhh + 2*HH + chB + g*4);

  float hreg[4] = {0.f,0.f,0.f,0.f};
  f16x8 cB = zf;            // bias/zero frag for g>=2
  if(g==2) cB[0] = (_Float16)1.0f;

  const int swz = (nd & 7) << 2;

  for(int t=0; t<TT; t++){
    const uint* cb = hb[t & 1];
    uint* nb = hb[(t & 1) ^ 1];

    f16x8 hB0 = *(const f16x8*)(cb + nd*32 + ((g*4)      ^ swz));
    f16x8 hB1 = *(const f16x8*)(cb + nd*32 + ((16 + g*4) ^ swz));
    f16x8 cAg = cB;
    if(g < 2) cAg = *(const f16x8*)&agg_lds[nd][t*16 + g*8];

    f32x4 R  = {0.f,0.f,0.f,0.f};
    f32x4 Z  = {0.f,0.f,0.f,0.f};
    f32x4 Nh = {0.f,0.f,0.f,0.f};
    f32x4 Ni = {0.f,0.f,0.f,0.f};
    R  = __builtin_amdgcn_mfma_f32_16x16x32_f16(ar0, hB0, R , 0,0,0);
    R  = __builtin_amdgcn_mfma_f32_16x16x32_f16(ar1, hB1, R , 0,0,0);
    R  = __builtin_amdgcn_mfma_f32_16x16x32_f16(mr,  cAg, R , 0,0,0);
    Z  = __builtin_amdgcn_mfma_f32_16x16x32_f16(az0, hB0, Z , 0,0,0);
    Z  = __builtin_amdgcn_mfma_f32_16x16x32_f16(az1, hB1, Z , 0,0,0);
    Z  = __builtin_amdgcn_mfma_f32_16x16x32_f16(mz,  cAg, Z , 0,0,0);
    Nh = __builtin_amdgcn_mfma_f32_16x16x32_f16(an0, hB0, Nh, 0,0,0);
    Nh = __builtin_amdgcn_mfma_f32_16x16x32_f16(an1, hB1, Nh, 0,0,0);
    Ni = __builtin_amdgcn_mfma_f32_16x16x32_f16(mn,  cAg, Ni, 0,0,0);

    const float bbv[4] = {bb.x, bb.y, bb.z, bb.w};
    #pragma unroll
    for(int i=0;i<4;i++){
      float r_ = sigmoid_f(R[i]);
      float z_ = sigmoid_f(Z[i]);
      float nn = tanh_f(Ni[i] + r_*(Nh[i] + bbv[i]));
      hreg[i] = nn + z_*(hreg[i] - nn);
    }
    if(t+1 < TT){
      uint2 pk;
      pk.x = pack_h2(hreg[0], hreg[1]);
      pk.y = pack_h2(hreg[2], hreg[3]);
      *(uint2*)(nb + nd*32 + ((8*w + 2*g) ^ swz)) = pk;
      __syncthreads();
    }
  }

  // ---- Phase C: fused linear head ----
  __syncthreads();   // all waves done with hb reads
  float* hs = (float*)hb;
  #pragma unroll
  for(int i=0;i<4;i++) hs[nd*64 + chB + g*4 + i] = hreg[i];
  __syncthreads();
  if(tid < 16*P){
    int ndl = tid & 15, p = tid >> 4;
    int node2 = nbase + ndl;
    if(node2 < N){
      float acc = lin_b[p];
      const float* hrow = hs + ndl*64;
      #pragma unroll
      for(int q=0;q<16;q++){
        float4 v = *(const float4*)(hrow + q*4);
        float4 lw = *(const float4*)(lin_w + p*HH + q*4);
        acc += v.x*lw.x + v.y*lw.y + v.z*lw.z + v.w*lw.w;
      }
      out[(size_t)p*N + node2] = acc;
    }
  }
}

extern "C" void kernel_launch(void* const* d_in, const int* in_sizes, int n_in,
                              void* d_out, int out_size, void* d_ws, size_t ws_size,
                              hipStream_t stream){
  const float* x     = (const float*)d_in[0];
  const float* gcn_w = (const float*)d_in[2];
  const float* gcn_b = (const float*)d_in[3];
  const float* w_ih  = (const float*)d_in[4];
  const float* w_hh  = (const float*)d_in[5];
  const float* b_ih  = (const float*)d_in[6];
  const float* b_hh  = (const float*)d_in[7];
  const float* lin_w = (const float*)d_in[8];
  const float* lin_b = (const float*)d_in[9];
  const int*   ei    = (const int*)d_in[10];
  const int E = in_sizes[10]/2;
  const int N = in_sizes[0]/(TT*FF);
  const int P = in_sizes[9];

  char* wsp = (char*)d_ws;
  auto alloc = [&](size_t bytes)->void*{ void* p = wsp; wsp += (bytes + 255) & ~(size_t)255; return p; };
  int*    cnt      = (int*)   alloc((size_t)N*4);
  ushort* dinvh    = (ushort*)alloc((size_t)N*2);
  ushort* ell      = (ushort*)alloc((size_t)N*ELLW*2);
  ushort* xTh      = (ushort*)alloc((size_t)(N+1)*384*2);   // +1 zero row
  ushort* m1F      = (ushort*)alloc((size_t)GG*FF*2);
  float*  c1       = (float*) alloc((size_t)GG*4);
  ushort* whhF     = (ushort*)alloc((size_t)GG*HH*2);

  hipMemsetAsync(cnt, 0, (size_t)N*4, stream);

  const int GX = (N + 15)/16;
  const int GD = (E + 255)/256;
  const int GP = (GG*HH + 255)/256;
  k_pre2 <<<GX + GD + GP, 256, 0, stream>>>(x, xTh, ei, E, cnt, ell,
                                            gcn_w, gcn_b, w_ih, b_ih, w_hh,
                                            m1F, c1, whhF, N, GX, GD);
  k_scale<<<((N+1)*192 + 255)/256, 256, 0, stream>>>(cnt, xTh, dinvh, N);
  k_fused<<<(N+15)/16, 256, 0, stream>>>(xTh, cnt, ell, dinvh, whhF, m1F, c1, b_hh,
                                         lin_w, lin_b, (float*)d_out, N, P);
}